// Round 1
// baseline (365.851 us; speedup 1.0000x reference)
//
#include <hip/hip_runtime.h>
#include <hip/hip_bf16.h>
#include <math.h>

#define SEQ    1024
#define DMODEL 512
#define DH     64
#define NH     8
#define NBAT   4
#define NBH    32
#define OUT0   2097152      // 4*1024*512 (output 0 size)
#define SP_EPS 1e-7f
#define INV_T  0.125f       // 1/sqrt(64)

// ---------------- block reduction helpers (256 threads = 4 waves) ----------
__device__ __forceinline__ float blk_max(float v, volatile float* red) {
#pragma unroll
  for (int o = 32; o > 0; o >>= 1) v = fmaxf(v, __shfl_xor(v, o));
  __syncthreads();
  if ((threadIdx.x & 63) == 0) red[threadIdx.x >> 6] = v;
  __syncthreads();
  return fmaxf(fmaxf(red[0], red[1]), fmaxf(red[2], red[3]));
}
__device__ __forceinline__ float blk_sum(float v, volatile float* red) {
#pragma unroll
  for (int o = 32; o > 0; o >>= 1) v += __shfl_xor(v, o);
  __syncthreads();
  if ((threadIdx.x & 63) == 0) red[threadIdx.x >> 6] = v;
  __syncthreads();
  return red[0] + red[1] + red[2] + red[3];
}

// ---------------- shared f32 GEMM body: C = A(Mx512) * W^T(512x512) --------
// BM=128 BN=64 BK=16, 256 threads, 8x4 micro-tile, k-major LDS.
__device__ __forceinline__ void gemm512_body(
    const float* __restrict__ A, const float* __restrict__ W,
    float (* __restrict__ As)[128], float (* __restrict__ Bs)[64],
    float acc[8][4], int r0, int n0)
{
  const int tid = threadIdx.x;
  const int lr = tid >> 2, lk4 = (tid & 3) * 4;
  const int ty = tid >> 4, tx = tid & 15;
  for (int k0 = 0; k0 < 512; k0 += 16) {
    __syncthreads();
    float4 a0 = *(const float4*)(A + (size_t)(r0 + lr) * 512 + k0 + lk4);
    float4 a1 = *(const float4*)(A + (size_t)(r0 + lr + 64) * 512 + k0 + lk4);
    float4 w0 = *(const float4*)(W + (size_t)(n0 + lr) * 512 + k0 + lk4);
    As[lk4+0][lr]    = a0.x; As[lk4+1][lr]    = a0.y; As[lk4+2][lr]    = a0.z; As[lk4+3][lr]    = a0.w;
    As[lk4+0][lr+64] = a1.x; As[lk4+1][lr+64] = a1.y; As[lk4+2][lr+64] = a1.z; As[lk4+3][lr+64] = a1.w;
    Bs[lk4+0][lr]    = w0.x; Bs[lk4+1][lr]    = w0.y; Bs[lk4+2][lr]    = w0.z; Bs[lk4+3][lr]    = w0.w;
    __syncthreads();
#pragma unroll
    for (int kk = 0; kk < 16; ++kk) {
      const float4 x0 = *(const float4*)&As[kk][ty * 8];
      const float4 x1 = *(const float4*)&As[kk][ty * 8 + 4];
      const float4 y  = *(const float4*)&Bs[kk][tx * 4];
      const float xa[8] = {x0.x, x0.y, x0.z, x0.w, x1.x, x1.y, x1.z, x1.w};
      const float yb[4] = {y.x, y.y, y.z, y.w};
#pragma unroll
      for (int i = 0; i < 8; ++i)
#pragma unroll
        for (int j = 0; j < 4; ++j)
          acc[i][j] = fmaf(xa[i], yb[j], acc[i][j]);
    }
  }
}

// ---------------- kernel 1: fused QKV projection (head-major output) -------
__global__ __launch_bounds__(256) void qkv_proj_kernel(
    const float* __restrict__ q, const float* __restrict__ k, const float* __restrict__ v,
    const float* __restrict__ Wq, const float* __restrict__ bq,
    const float* __restrict__ Wk, const float* __restrict__ bk,
    const float* __restrict__ Wv, const float* __restrict__ bv,
    float* __restrict__ qh, float* __restrict__ kh, float* __restrict__ vh)
{
  __shared__ float As[16][128];
  __shared__ float Bs[16][64];
  const int z = blockIdx.z;
  const float* A    = (z == 0) ? q  : (z == 1) ? k  : v;
  const float* W    = (z == 0) ? Wq : (z == 1) ? Wk : Wv;
  const float* bias = (z == 0) ? bq : (z == 1) ? bk : bv;
  float* C          = (z == 0) ? qh : (z == 1) ? kh : vh;
  const int r0 = blockIdx.x * 128, n0 = blockIdx.y * 64;
  float acc[8][4] = {};
  gemm512_body(A, W, As, Bs, acc, r0, n0);
  const int ty = threadIdx.x >> 4, tx = threadIdx.x & 15;
  const int c = n0 + tx * 4;
  const int h = c >> 6, d = c & 63;
  const float4 bv4 = *(const float4*)(bias + c);
#pragma unroll
  for (int i = 0; i < 8; ++i) {
    const int r = r0 + ty * 8 + i;
    const int b = r >> 10, l = r & 1023;
    float4 o;
    o.x = acc[i][0] + bv4.x; o.y = acc[i][1] + bv4.y;
    o.z = acc[i][2] + bv4.z; o.w = acc[i][3] + bv4.w;
    // head-major: [(h*NBAT+b)][l][d]
    *(float4*)(C + ((size_t)(h * NBAT + b) << 16) + ((size_t)l << 6) + d) = o;
  }
}

// ---------------- kernel 2: scores = qh @ kh^T / sqrt(dk) ------------------
// per bh: (1024x64)x(64x1024); BM=128 BN=64, K=64 single tile.
__global__ __launch_bounds__(256) void scores_kernel(
    const float* __restrict__ qh, const float* __restrict__ kh,
    float* __restrict__ attn)
{
  __shared__ float As[64][128];
  __shared__ float Bs[64][64];
  const int bh = blockIdx.z;
  const int r0 = blockIdx.x * 128, c0 = blockIdx.y * 64;
  const float* Aq = qh + ((size_t)bh << 16);
  const float* Bk = kh + ((size_t)bh << 16);
  const int tid = threadIdx.x;
  const int sr = tid & 15, sk4 = (tid >> 4) * 4;   // row-spread for bank-friendly LDS writes
#pragma unroll
  for (int p = 0; p < 8; ++p) {
    const int rr = sr + p * 16;
    float4 a = *(const float4*)(Aq + (size_t)(r0 + rr) * 64 + sk4);
    As[sk4+0][rr] = a.x; As[sk4+1][rr] = a.y; As[sk4+2][rr] = a.z; As[sk4+3][rr] = a.w;
  }
#pragma unroll
  for (int p = 0; p < 4; ++p) {
    const int rr = sr + p * 16;
    float4 b = *(const float4*)(Bk + (size_t)(c0 + rr) * 64 + sk4);
    Bs[sk4+0][rr] = b.x; Bs[sk4+1][rr] = b.y; Bs[sk4+2][rr] = b.z; Bs[sk4+3][rr] = b.w;
  }
  __syncthreads();
  const int ty = tid >> 4, tx = tid & 15;
  float acc[8][4] = {};
#pragma unroll 8
  for (int kk = 0; kk < 64; ++kk) {
    const float4 x0 = *(const float4*)&As[kk][ty * 8];
    const float4 x1 = *(const float4*)&As[kk][ty * 8 + 4];
    const float4 y  = *(const float4*)&Bs[kk][tx * 4];
    const float xa[8] = {x0.x, x0.y, x0.z, x0.w, x1.x, x1.y, x1.z, x1.w};
    const float yb[4] = {y.x, y.y, y.z, y.w};
#pragma unroll
    for (int i = 0; i < 8; ++i)
#pragma unroll
      for (int j = 0; j < 4; ++j)
        acc[i][j] = fmaf(xa[i], yb[j], acc[i][j]);
  }
  float* outp = attn + ((size_t)bh << 20);
#pragma unroll
  for (int i = 0; i < 8; ++i) {
    const int r = r0 + ty * 8 + i;
    float4 o = make_float4(acc[i][0] * INV_T, acc[i][1] * INV_T,
                           acc[i][2] * INV_T, acc[i][3] * INV_T);
    *(float4*)(outp + (size_t)r * 1024 + c0 + tx * 4) = o;
  }
}

// ---------------- kernel 3: softmax + top-6 sparsify + sparse PV -----------
// one block per (bh, lq) row; scores in-place -> sparse weights; PV via <=5 gathers.
__global__ __launch_bounds__(256) void sparse_row_kernel(
    float* __restrict__ attn, const float* __restrict__ vh,
    float* __restrict__ out_full)
{
  const int row = blockIdx.x;            // bh*1024 + lq
  const int tid = threadIdx.x;
  const int bh = row >> 10, lq = row & 1023;
  float* rp = attn + ((size_t)row << 10);
  __shared__ float red[4];
  __shared__ int   claim, cnt;
  __shared__ float swv[8];
  __shared__ int   swi[8];

  float4 s4 = *(const float4*)(rp + tid * 4);
  float s[4] = {s4.x, s4.y, s4.z, s4.w};

  float m = fmaxf(fmaxf(s[0], s[1]), fmaxf(s[2], s[3]));
  m = blk_max(m, red);
  float p[4], ls = 0.f;
#pragma unroll
  for (int j = 0; j < 4; ++j) { p[j] = expf(s[j] - m); ls += p[j]; }
  const float Z = blk_sum(ls, red);
  const float invZ = 1.0f / Z;
#pragma unroll
  for (int j = 0; j < 4; ++j) p[j] *= invZ;

  // top-6 (with duplicate multiplicity, like lax.top_k): 6x max + remove-one
  bool rem[4] = {false, false, false, false};
  float p6 = 0.f;
  for (int it = 0; it < 6; ++it) {
    float lm = -1.0f;
#pragma unroll
    for (int j = 0; j < 4; ++j) if (!rem[j]) lm = fmaxf(lm, p[j]);
    const float mm = blk_max(lm, red);
    if (it == 5) { p6 = mm; break; }
    if (tid == 0) claim = 0;
    __syncthreads();
#pragma unroll
    for (int j = 0; j < 4; ++j)
      if (!rem[j] && p[j] == mm) { if (atomicAdd(&claim, 1) == 0) rem[j] = true; }
    __syncthreads();
  }

  const float delta = p6 + SP_EPS;
  float w[4], lw = 0.f;
#pragma unroll
  for (int j = 0; j < 4; ++j) { w[j] = fmaxf(p[j] - delta, 0.f); lw += w[j]; }
  const float Wsum = blk_sum(lw, red);
  const float inv = 1.0f / (Wsum + SP_EPS);
  float wo[4];
#pragma unroll
  for (int j = 0; j < 4; ++j) wo[j] = w[j] * inv;
  *(float4*)(rp + tid * 4) = make_float4(wo[0], wo[1], wo[2], wo[3]);

  // gather nonzeros (<=5)
  if (tid == 0) cnt = 0;
  __syncthreads();
#pragma unroll
  for (int j = 0; j < 4; ++j)
    if (wo[j] > 0.f) {
      const int pos = atomicAdd(&cnt, 1);
      if (pos < 8) { swv[pos] = wo[j]; swi[pos] = tid * 4 + j; }
    }
  __syncthreads();
  if (tid == 0) {   // sort by index for run-to-run determinism
    const int n = min(cnt, 8);
    for (int a = 0; a < n; ++a)
      for (int bql = a + 1; bql < n; ++bql)
        if (swi[bql] < swi[a]) {
          int ti = swi[a]; swi[a] = swi[bql]; swi[bql] = ti;
          float tv = swv[a]; swv[a] = swv[bql]; swv[bql] = tv;
        }
  }
  __syncthreads();
  if (tid < 64) {
    const int n = min(cnt, 8);
    const float* vb = vh + ((size_t)bh << 16);
    float acc = 0.f;
    for (int t = 0; t < n; ++t) acc = fmaf(swv[t], vb[((size_t)swi[t] << 6) + tid], acc);
    const int b = bh & 3, h = bh >> 2;
    out_full[((size_t)((b << 10) | lq) << 9) + (h << 6) + tid] = acc;
  }
}

// ---------------- kernel 4: fc & gate GEMMs --------------------------------
__global__ __launch_bounds__(256) void out_proj_kernel(
    const float* __restrict__ A,
    const float* __restrict__ Wfc, const float* __restrict__ bfc,
    const float* __restrict__ Wg,  const float* __restrict__ bg,
    float* __restrict__ fcb, float* __restrict__ gb)
{
  __shared__ float As[16][128];
  __shared__ float Bs[16][64];
  const int z = blockIdx.z;
  const float* W    = z ? Wg : Wfc;
  const float* bias = z ? bg : bfc;
  float* C          = z ? gb : fcb;
  const int r0 = blockIdx.x * 128, n0 = blockIdx.y * 64;
  float acc[8][4] = {};
  gemm512_body(A, W, As, Bs, acc, r0, n0);
  const int ty = threadIdx.x >> 4, tx = threadIdx.x & 15;
  const int c = n0 + tx * 4;
  const float4 bv4 = *(const float4*)(bias + c);
#pragma unroll
  for (int i = 0; i < 8; ++i) {
    const int r = r0 + ty * 8 + i;
    float4 o;
    o.x = acc[i][0] + bv4.x; o.y = acc[i][1] + bv4.y;
    o.z = acc[i][2] + bv4.z; o.w = acc[i][3] + bv4.w;
    *(float4*)(C + (size_t)r * 512 + c) = o;
  }
}

// ---------------- kernel 5: out = sigmoid(gate) * tanh(fc) -----------------
__global__ __launch_bounds__(256) void gate_combine_kernel(
    const float* __restrict__ fcb, const float* __restrict__ gb,
    float* __restrict__ out)
{
  const size_t i = ((size_t)blockIdx.x * 256 + threadIdx.x) * 4;
  float4 f = *(const float4*)(fcb + i);
  float4 g = *(const float4*)(gb + i);
  float4 o;
  o.x = tanhf(f.x) / (1.f + expf(-g.x));
  o.y = tanhf(f.y) / (1.f + expf(-g.y));
  o.z = tanhf(f.z) / (1.f + expf(-g.z));
  o.w = tanhf(f.w) / (1.f + expf(-g.w));
  *(float4*)(out + i) = o;
}

extern "C" void kernel_launch(void* const* d_in, const int* in_sizes, int n_in,
                              void* d_out, int out_size, void* d_ws, size_t ws_size,
                              hipStream_t stream) {
  const float* q   = (const float*)d_in[0];
  const float* k   = (const float*)d_in[1];
  const float* v   = (const float*)d_in[2];
  const float* Wq  = (const float*)d_in[3];
  const float* bq  = (const float*)d_in[4];
  const float* Wk  = (const float*)d_in[5];
  const float* bk  = (const float*)d_in[6];
  const float* Wv  = (const float*)d_in[7];
  const float* bv  = (const float*)d_in[8];
  const float* Wfc = (const float*)d_in[9];
  const float* bfc = (const float*)d_in[10];
  const float* Wg  = (const float*)d_in[11];
  const float* bg  = (const float*)d_in[12];

  float* out  = (float*)d_out;
  float* attn = out + OUT0;                 // (32,1024,1024) — used as score scratch then final
  float* ws   = (float*)d_ws;
  float* qh = ws;                           // 2M floats each
  float* kh = ws + (1u << 21);
  float* vh = ws + (2u << 21);
  float* out_full = qh;                     // overlay: qh dead after scores
  float* fcb = kh;                          // overlay: kh dead after scores
  float* gb  = vh;                          // overlay: vh dead after sparse_row

  qkv_proj_kernel<<<dim3(32, 8, 3), 256, 0, stream>>>(q, k, v, Wq, bq, Wk, bk, Wv, bv, qh, kh, vh);
  scores_kernel<<<dim3(8, 16, 32), 256, 0, stream>>>(qh, kh, attn);
  sparse_row_kernel<<<dim3(32768), 256, 0, stream>>>(attn, vh, out_full);
  out_proj_kernel<<<dim3(32, 8, 2), 256, 0, stream>>>(out_full, Wfc, bfc, Wg, bg, fcb, gb);
  gate_combine_kernel<<<dim3(2048), 256, 0, stream>>>(fcb, gb, out);
}

// Round 2
// 269.414 us; speedup vs baseline: 1.3579x; 1.3579x over previous
//
#include <hip/hip_runtime.h>
#include <hip/hip_bf16.h>
#include <math.h>

#define SEQ    1024
#define DMODEL 512
#define DH     64
#define NH     8
#define NBAT   4
#define NBH    32
#define OUT0   2097152      // 4*1024*512 (output 0 size)
#define SP_EPS 1e-7f
#define INV_T  0.125f       // 1/sqrt(64)

// ---------------- wave (64-lane) reduction helpers, barrier-free -----------
__device__ __forceinline__ float wred_max(float v) {
#pragma unroll
  for (int o = 32; o > 0; o >>= 1) v = fmaxf(v, __shfl_xor(v, o));
  return v;
}
__device__ __forceinline__ float wred_sum(float v) {
#pragma unroll
  for (int o = 32; o > 0; o >>= 1) v += __shfl_xor(v, o);
  return v;
}

// ---------------- shared f32 GEMM body: C = A(Mx512) * W^T(512x512) --------
// BM=128 BN=64 BK=16, 256 threads, 8x4 micro-tile, k-major LDS.
__device__ __forceinline__ void gemm512_body(
    const float* __restrict__ A, const float* __restrict__ W,
    float (* __restrict__ As)[128], float (* __restrict__ Bs)[64],
    float acc[8][4], int r0, int n0)
{
  const int tid = threadIdx.x;
  const int lr = tid >> 2, lk4 = (tid & 3) * 4;
  const int ty = tid >> 4, tx = tid & 15;
  for (int k0 = 0; k0 < 512; k0 += 16) {
    __syncthreads();
    float4 a0 = *(const float4*)(A + (size_t)(r0 + lr) * 512 + k0 + lk4);
    float4 a1 = *(const float4*)(A + (size_t)(r0 + lr + 64) * 512 + k0 + lk4);
    float4 w0 = *(const float4*)(W + (size_t)(n0 + lr) * 512 + k0 + lk4);
    As[lk4+0][lr]    = a0.x; As[lk4+1][lr]    = a0.y; As[lk4+2][lr]    = a0.z; As[lk4+3][lr]    = a0.w;
    As[lk4+0][lr+64] = a1.x; As[lk4+1][lr+64] = a1.y; As[lk4+2][lr+64] = a1.z; As[lk4+3][lr+64] = a1.w;
    Bs[lk4+0][lr]    = w0.x; Bs[lk4+1][lr]    = w0.y; Bs[lk4+2][lr]    = w0.z; Bs[lk4+3][lr]    = w0.w;
    __syncthreads();
#pragma unroll
    for (int kk = 0; kk < 16; ++kk) {
      const float4 x0 = *(const float4*)&As[kk][ty * 8];
      const float4 x1 = *(const float4*)&As[kk][ty * 8 + 4];
      const float4 y  = *(const float4*)&Bs[kk][tx * 4];
      const float xa[8] = {x0.x, x0.y, x0.z, x0.w, x1.x, x1.y, x1.z, x1.w};
      const float yb[4] = {y.x, y.y, y.z, y.w};
#pragma unroll
      for (int i = 0; i < 8; ++i)
#pragma unroll
        for (int j = 0; j < 4; ++j)
          acc[i][j] = fmaf(xa[i], yb[j], acc[i][j]);
    }
  }
}

// ---------------- kernel 1: fused QKV projection (head-major output) -------
__global__ __launch_bounds__(256) void qkv_proj_kernel(
    const float* __restrict__ q, const float* __restrict__ k, const float* __restrict__ v,
    const float* __restrict__ Wq, const float* __restrict__ bq,
    const float* __restrict__ Wk, const float* __restrict__ bk,
    const float* __restrict__ Wv, const float* __restrict__ bv,
    float* __restrict__ qh, float* __restrict__ kh, float* __restrict__ vh)
{
  __shared__ float As[16][128];
  __shared__ float Bs[16][64];
  const int z = blockIdx.z;
  const float* A    = (z == 0) ? q  : (z == 1) ? k  : v;
  const float* W    = (z == 0) ? Wq : (z == 1) ? Wk : Wv;
  const float* bias = (z == 0) ? bq : (z == 1) ? bk : bv;
  float* C          = (z == 0) ? qh : (z == 1) ? kh : vh;
  const int r0 = blockIdx.x * 128, n0 = blockIdx.y * 64;
  float acc[8][4] = {};
  gemm512_body(A, W, As, Bs, acc, r0, n0);
  const int ty = threadIdx.x >> 4, tx = threadIdx.x & 15;
  const int c = n0 + tx * 4;
  const int h = c >> 6, d = c & 63;
  const float4 bv4 = *(const float4*)(bias + c);
#pragma unroll
  for (int i = 0; i < 8; ++i) {
    const int r = r0 + ty * 8 + i;
    const int b = r >> 10, l = r & 1023;
    float4 o;
    o.x = acc[i][0] + bv4.x; o.y = acc[i][1] + bv4.y;
    o.z = acc[i][2] + bv4.z; o.w = acc[i][3] + bv4.w;
    // head-major: [(h*NBAT+b)][l][d]
    *(float4*)(C + ((size_t)(h * NBAT + b) << 16) + ((size_t)l << 6) + d) = o;
  }
}

// ---------------- kernel 2: scores = qh @ kh^T / sqrt(dk) ------------------
// per bh: (1024x64)x(64x1024); BM=128 BN=64, K=64 single tile.
__global__ __launch_bounds__(256) void scores_kernel(
    const float* __restrict__ qh, const float* __restrict__ kh,
    float* __restrict__ attn)
{
  __shared__ float As[64][128];
  __shared__ float Bs[64][64];
  const int bh = blockIdx.z;
  const int r0 = blockIdx.x * 128, c0 = blockIdx.y * 64;
  const float* Aq = qh + ((size_t)bh << 16);
  const float* Bk = kh + ((size_t)bh << 16);
  const int tid = threadIdx.x;
  const int sr = tid & 15, sk4 = (tid >> 4) * 4;
#pragma unroll
  for (int p = 0; p < 8; ++p) {
    const int rr = sr + p * 16;
    float4 a = *(const float4*)(Aq + (size_t)(r0 + rr) * 64 + sk4);
    As[sk4+0][rr] = a.x; As[sk4+1][rr] = a.y; As[sk4+2][rr] = a.z; As[sk4+3][rr] = a.w;
  }
#pragma unroll
  for (int p = 0; p < 4; ++p) {
    const int rr = sr + p * 16;
    float4 b = *(const float4*)(Bk + (size_t)(c0 + rr) * 64 + sk4);
    Bs[sk4+0][rr] = b.x; Bs[sk4+1][rr] = b.y; Bs[sk4+2][rr] = b.z; Bs[sk4+3][rr] = b.w;
  }
  __syncthreads();
  const int ty = tid >> 4, tx = tid & 15;
  float acc[8][4] = {};
#pragma unroll 8
  for (int kk = 0; kk < 64; ++kk) {
    const float4 x0 = *(const float4*)&As[kk][ty * 8];
    const float4 x1 = *(const float4*)&As[kk][ty * 8 + 4];
    const float4 y  = *(const float4*)&Bs[kk][tx * 4];
    const float xa[8] = {x0.x, x0.y, x0.z, x0.w, x1.x, x1.y, x1.z, x1.w};
    const float yb[4] = {y.x, y.y, y.z, y.w};
#pragma unroll
    for (int i = 0; i < 8; ++i)
#pragma unroll
      for (int j = 0; j < 4; ++j)
        acc[i][j] = fmaf(xa[i], yb[j], acc[i][j]);
  }
  float* outp = attn + ((size_t)bh << 20);
#pragma unroll
  for (int i = 0; i < 8; ++i) {
    const int r = r0 + ty * 8 + i;
    float4 o = make_float4(acc[i][0] * INV_T, acc[i][1] * INV_T,
                           acc[i][2] * INV_T, acc[i][3] * INV_T);
    *(float4*)(outp + (size_t)r * 1024 + c0 + tx * 4) = o;
  }
}

// ---------------- kernel 3: softmax + top-6 sparsify + sparse PV -----------
// WAVE-synchronous: one 64-lane wave per row, 16 probs/lane, zero barriers.
// Tie indices never matter (w = max(p - delta, 0) is elementwise); only the
// 6th-largest VALUE with multiplicity is needed -> remove-one x5, then max.
__global__ __launch_bounds__(256) void sparse_row_kernel(
    float* __restrict__ attn, const float* __restrict__ vh,
    float* __restrict__ out_full)
{
  const int tid  = threadIdx.x;
  const int wv   = tid >> 6, lane = tid & 63;
  const int row  = blockIdx.x * 4 + wv;          // bh*1024 + lq
  const int bh   = row >> 10, lq = row & 1023;
  float* rp = attn + ((size_t)row << 10);
  __shared__ float s_w[4][8];
  __shared__ int   s_i[4][8];

  // load 16 probs: col(j) = (j>>2)*256 + lane*4 + (j&3)  (coalesced float4)
  float p[16];
  {
    const float4 t0 = *(const float4*)(rp + lane * 4);
    const float4 t1 = *(const float4*)(rp + 256 + lane * 4);
    const float4 t2 = *(const float4*)(rp + 512 + lane * 4);
    const float4 t3 = *(const float4*)(rp + 768 + lane * 4);
    p[0]=t0.x; p[1]=t0.y; p[2]=t0.z; p[3]=t0.w;
    p[4]=t1.x; p[5]=t1.y; p[6]=t1.z; p[7]=t1.w;
    p[8]=t2.x; p[9]=t2.y; p[10]=t2.z; p[11]=t2.w;
    p[12]=t3.x; p[13]=t3.y; p[14]=t3.z; p[15]=t3.w;
  }

  float m = -1e30f;
#pragma unroll
  for (int j = 0; j < 16; ++j) m = fmaxf(m, p[j]);
  m = wred_max(m);
  float Z = 0.f;
#pragma unroll
  for (int j = 0; j < 16; ++j) { p[j] = __expf(p[j] - m); Z += p[j]; }
  Z = wred_sum(Z);
  const float invZ = 1.0f / Z;
#pragma unroll
  for (int j = 0; j < 16; ++j) p[j] *= invZ;

  // 6th largest with multiplicity: 5x (wave-max + remove one instance), then max
  unsigned rem = 0;
  float p6 = 0.f;
  for (int it = 0; it < 6; ++it) {
    float lm = -1.f;
#pragma unroll
    for (int j = 0; j < 16; ++j) if (!((rem >> j) & 1u)) lm = fmaxf(lm, p[j]);
    const float mm = wred_max(lm);
    if (it == 5) { p6 = mm; break; }
    const unsigned long long b = __ballot(lm == mm);
    if (lane == (__ffsll((long long)b) - 1)) {
      bool done = false;
#pragma unroll
      for (int j = 0; j < 16; ++j)
        if (!done && !((rem >> j) & 1u) && p[j] == mm) { rem |= (1u << j); done = true; }
    }
  }

  const float delta = p6 + SP_EPS;
  float w[16], lw = 0.f;
#pragma unroll
  for (int j = 0; j < 16; ++j) { w[j] = fmaxf(p[j] - delta, 0.f); lw += w[j]; }
  const float Wsum = wred_sum(lw);
  const float inv = 1.0f / (Wsum + SP_EPS);
#pragma unroll
  for (int j = 0; j < 16; ++j) w[j] *= inv;

  // store sparse weights (full row, mostly zeros)
  *(float4*)(rp +       lane * 4) = make_float4(w[0],  w[1],  w[2],  w[3]);
  *(float4*)(rp + 256 + lane * 4) = make_float4(w[4],  w[5],  w[6],  w[7]);
  *(float4*)(rp + 512 + lane * 4) = make_float4(w[8],  w[9],  w[10], w[11]);
  *(float4*)(rp + 768 + lane * 4) = make_float4(w[12], w[13], w[14], w[15]);

  // collect <=5 nonzeros via deterministic ballot prefix into per-wave LDS
  int base = 0;
#pragma unroll
  for (int j = 0; j < 16; ++j) {
    const unsigned long long b = __ballot(w[j] > 0.f);
    if (w[j] > 0.f) {
      const int pos = base + __popcll(b & ((1ull << lane) - 1ull));
      if (pos < 8) { s_w[wv][pos] = w[j]; s_i[wv][pos] = (j >> 2) * 256 + lane * 4 + (j & 3); }
    }
    base += __popcll(b);
  }
  if (base > 8) base = 8;

  // sparse PV: lane = output dim; <=5 coalesced 256B V-row gathers
  float acc = 0.f;
  const float* vb = vh + ((size_t)bh << 16);
  for (int t = 0; t < base; ++t)
    acc = fmaf(s_w[wv][t], vb[((size_t)s_i[wv][t] << 6) + lane], acc);
  const int b_ = bh & 3, h = bh >> 2;
  out_full[((size_t)((b_ << 10) | lq) << 9) + (h << 6) + lane] = acc;
}

// ---------------- kernel 4: fused fc+gate GEMMs + sigmoid*tanh epilogue ----
__global__ __launch_bounds__(256) void out_proj_fused_kernel(
    const float* __restrict__ A,
    const float* __restrict__ Wfc, const float* __restrict__ bfc,
    const float* __restrict__ Wg,  const float* __restrict__ bg,
    float* __restrict__ out)
{
  __shared__ float As[16][128];
  __shared__ float Bf[16][64];
  __shared__ float Bg[16][64];
  const int r0 = blockIdx.x * 128, n0 = blockIdx.y * 64;
  const int tid = threadIdx.x;
  const int lr = tid >> 2, lk4 = (tid & 3) * 4;
  const int ty = tid >> 4, tx = tid & 15;
  float accf[8][4] = {}, accg[8][4] = {};
  for (int k0 = 0; k0 < 512; k0 += 16) {
    __syncthreads();
    float4 a0 = *(const float4*)(A   + (size_t)(r0 + lr) * 512 + k0 + lk4);
    float4 a1 = *(const float4*)(A   + (size_t)(r0 + lr + 64) * 512 + k0 + lk4);
    float4 wf = *(const float4*)(Wfc + (size_t)(n0 + lr) * 512 + k0 + lk4);
    float4 wg = *(const float4*)(Wg  + (size_t)(n0 + lr) * 512 + k0 + lk4);
    As[lk4+0][lr]    = a0.x; As[lk4+1][lr]    = a0.y; As[lk4+2][lr]    = a0.z; As[lk4+3][lr]    = a0.w;
    As[lk4+0][lr+64] = a1.x; As[lk4+1][lr+64] = a1.y; As[lk4+2][lr+64] = a1.z; As[lk4+3][lr+64] = a1.w;
    Bf[lk4+0][lr]    = wf.x; Bf[lk4+1][lr]    = wf.y; Bf[lk4+2][lr]    = wf.z; Bf[lk4+3][lr]    = wf.w;
    Bg[lk4+0][lr]    = wg.x; Bg[lk4+1][lr]    = wg.y; Bg[lk4+2][lr]    = wg.z; Bg[lk4+3][lr]    = wg.w;
    __syncthreads();
#pragma unroll
    for (int kk = 0; kk < 16; ++kk) {
      const float4 x0 = *(const float4*)&As[kk][ty * 8];
      const float4 x1 = *(const float4*)&As[kk][ty * 8 + 4];
      const float4 yf = *(const float4*)&Bf[kk][tx * 4];
      const float4 yg = *(const float4*)&Bg[kk][tx * 4];
      const float xa[8] = {x0.x, x0.y, x0.z, x0.w, x1.x, x1.y, x1.z, x1.w};
      const float yfb[4] = {yf.x, yf.y, yf.z, yf.w};
      const float ygb[4] = {yg.x, yg.y, yg.z, yg.w};
#pragma unroll
      for (int i = 0; i < 8; ++i)
#pragma unroll
        for (int j = 0; j < 4; ++j) {
          accf[i][j] = fmaf(xa[i], yfb[j], accf[i][j]);
          accg[i][j] = fmaf(xa[i], ygb[j], accg[i][j]);
        }
    }
  }
  const int c = n0 + tx * 4;
  const float4 bf4 = *(const float4*)(bfc + c);
  const float4 bg4 = *(const float4*)(bg + c);
#pragma unroll
  for (int i = 0; i < 8; ++i) {
    const int r = r0 + ty * 8 + i;
    float4 o;
    o.x = tanhf(accf[i][0] + bf4.x) / (1.f + __expf(-(accg[i][0] + bg4.x)));
    o.y = tanhf(accf[i][1] + bf4.y) / (1.f + __expf(-(accg[i][1] + bg4.y)));
    o.z = tanhf(accf[i][2] + bf4.z) / (1.f + __expf(-(accg[i][2] + bg4.z)));
    o.w = tanhf(accf[i][3] + bf4.w) / (1.f + __expf(-(accg[i][3] + bg4.w)));
    *(float4*)(out + (size_t)r * 512 + c) = o;
  }
}

extern "C" void kernel_launch(void* const* d_in, const int* in_sizes, int n_in,
                              void* d_out, int out_size, void* d_ws, size_t ws_size,
                              hipStream_t stream) {
  const float* q   = (const float*)d_in[0];
  const float* k   = (const float*)d_in[1];
  const float* v   = (const float*)d_in[2];
  const float* Wq  = (const float*)d_in[3];
  const float* bq  = (const float*)d_in[4];
  const float* Wk  = (const float*)d_in[5];
  const float* bk  = (const float*)d_in[6];
  const float* Wv  = (const float*)d_in[7];
  const float* bv  = (const float*)d_in[8];
  const float* Wfc = (const float*)d_in[9];
  const float* bfc = (const float*)d_in[10];
  const float* Wg  = (const float*)d_in[11];
  const float* bg  = (const float*)d_in[12];

  float* out  = (float*)d_out;
  float* attn = out + OUT0;                 // (32,1024,1024) — score scratch then final
  float* ws   = (float*)d_ws;
  float* qh = ws;                           // 2M floats each
  float* kh = ws + (1u << 21);
  float* vh = ws + (2u << 21);
  float* out_full = qh;                     // overlay: qh dead after scores

  qkv_proj_kernel<<<dim3(32, 8, 3), 256, 0, stream>>>(q, k, v, Wq, bq, Wk, bk, Wv, bv, qh, kh, vh);
  scores_kernel<<<dim3(8, 16, 32), 256, 0, stream>>>(qh, kh, attn);
  sparse_row_kernel<<<dim3(8192), 256, 0, stream>>>(attn, vh, out_full);
  out_proj_fused_kernel<<<dim3(32, 8), 256, 0, stream>>>(out_full, Wfc, bfc, Wg, bg, out);
}

// Round 3
// 257.908 us; speedup vs baseline: 1.4185x; 1.0446x over previous
//
#include <hip/hip_runtime.h>
#include <hip/hip_bf16.h>
#include <math.h>

#define SEQ    1024
#define DMODEL 512
#define DH     64
#define NH     8
#define NBAT   4
#define NBH    32
#define OUT0   2097152      // 4*1024*512 (output 0 size)
#define SP_EPS 1e-7f
#define INV_T  0.125f       // 1/sqrt(64)

// ---------------- wave (64-lane) reduction helpers, barrier-free -----------
__device__ __forceinline__ float wred_max(float v) {
#pragma unroll
  for (int o = 32; o > 0; o >>= 1) v = fmaxf(v, __shfl_xor(v, o));
  return v;
}
__device__ __forceinline__ float wred_sum(float v) {
#pragma unroll
  for (int o = 32; o > 0; o >>= 1) v += __shfl_xor(v, o);
  return v;
}

// LDS column swizzle: k-major tile [32][64]; flipping bit4 of the column by
// (k>>3)&1 makes the 4 k-group writers hit 2-way-aliased banks (free) while
// keeping float4 reads 16B-aligned.
__device__ __forceinline__ int swz(int k, int m) { return m ^ (((k >> 3) & 1) << 4); }

// ---------------- 64x64 tile f32 GEMM: C = A(Mx512) * W^T(512(N)x512(K)) ---
// BK=32, 256 threads, 4x4 micro-tile. acc indexed [row][col].
__device__ __forceinline__ void gemm64_body(
    const float* __restrict__ A, const float* __restrict__ W,
    float (* __restrict__ As)[64], float (* __restrict__ Bs)[64],
    float acc[4][4], int r0, int n0)
{
  const int tid = threadIdx.x;
  const int lr = tid >> 2, lk8 = (tid & 3) * 8;
  const int ty = tid >> 4, tx = tid & 15;
  const int sa = (lk8 >> 3) & 1;  // swizzle bit for this thread's k-group
  for (int k0 = 0; k0 < 512; k0 += 32) {
    __syncthreads();
    const float4 a0 = *(const float4*)(A + (size_t)(r0 + lr) * 512 + k0 + lk8);
    const float4 a1 = *(const float4*)(A + (size_t)(r0 + lr) * 512 + k0 + lk8 + 4);
    const float4 w0 = *(const float4*)(W + (size_t)(n0 + lr) * 512 + k0 + lk8);
    const float4 w1 = *(const float4*)(W + (size_t)(n0 + lr) * 512 + k0 + lk8 + 4);
    const int c = lr ^ (sa << 4);
    As[lk8+0][c] = a0.x; As[lk8+1][c] = a0.y; As[lk8+2][c] = a0.z; As[lk8+3][c] = a0.w;
    As[lk8+4][c] = a1.x; As[lk8+5][c] = a1.y; As[lk8+6][c] = a1.z; As[lk8+7][c] = a1.w;
    Bs[lk8+0][c] = w0.x; Bs[lk8+1][c] = w0.y; Bs[lk8+2][c] = w0.z; Bs[lk8+3][c] = w0.w;
    Bs[lk8+4][c] = w1.x; Bs[lk8+5][c] = w1.y; Bs[lk8+6][c] = w1.z; Bs[lk8+7][c] = w1.w;
    __syncthreads();
#pragma unroll
    for (int kk = 0; kk < 32; ++kk) {
      const float4 x = *(const float4*)&As[kk][swz(kk, ty * 4)];
      const float4 y = *(const float4*)&Bs[kk][swz(kk, tx * 4)];
      const float xa[4] = {x.x, x.y, x.z, x.w};
      const float yb[4] = {y.x, y.y, y.z, y.w};
#pragma unroll
      for (int i = 0; i < 4; ++i)
#pragma unroll
        for (int j = 0; j < 4; ++j)
          acc[i][j] = fmaf(xa[i], yb[j], acc[i][j]);
    }
  }
}

// ---------------- kernel 1: fused QKV projection (head-major output) -------
__global__ __launch_bounds__(256) void qkv_proj_kernel(
    const float* __restrict__ q, const float* __restrict__ k, const float* __restrict__ v,
    const float* __restrict__ Wq, const float* __restrict__ bq,
    const float* __restrict__ Wk, const float* __restrict__ bk,
    const float* __restrict__ Wv, const float* __restrict__ bv,
    float* __restrict__ qh, float* __restrict__ kh, float* __restrict__ vh)
{
  __shared__ float As[32][64];
  __shared__ float Bs[32][64];
  const int z = blockIdx.z;
  const float* A    = (z == 0) ? q  : (z == 1) ? k  : v;
  const float* W    = (z == 0) ? Wq : (z == 1) ? Wk : Wv;
  const float* bias = (z == 0) ? bq : (z == 1) ? bk : bv;
  float* C          = (z == 0) ? qh : (z == 1) ? kh : vh;
  const int r0 = blockIdx.x * 64, n0 = blockIdx.y * 64;
  float acc[4][4] = {};
  gemm64_body(A, W, As, Bs, acc, r0, n0);
  const int ty = threadIdx.x >> 4, tx = threadIdx.x & 15;
  const int c = n0 + tx * 4;
  const int h = c >> 6, d = c & 63;
  const float4 bv4 = *(const float4*)(bias + c);
#pragma unroll
  for (int i = 0; i < 4; ++i) {
    const int r = r0 + ty * 4 + i;
    const int b = r >> 10, l = r & 1023;
    float4 o;
    o.x = acc[i][0] + bv4.x; o.y = acc[i][1] + bv4.y;
    o.z = acc[i][2] + bv4.z; o.w = acc[i][3] + bv4.w;
    *(float4*)(C + ((size_t)(h * NBAT + b) << 16) + ((size_t)l << 6) + d) = o;
  }
}

// ---------------- kernel 2: scores = qh @ kh^T / sqrt(dk) ------------------
__global__ __launch_bounds__(256) void scores_kernel(
    const float* __restrict__ qh, const float* __restrict__ kh,
    float* __restrict__ attn)
{
  __shared__ float As[64][128];
  __shared__ float Bs[64][64];
  const int bh = blockIdx.z;
  const int r0 = blockIdx.x * 128, c0 = blockIdx.y * 64;
  const float* Aq = qh + ((size_t)bh << 16);
  const float* Bk = kh + ((size_t)bh << 16);
  const int tid = threadIdx.x;
  const int sr = tid & 15, sk4 = (tid >> 4) * 4;
#pragma unroll
  for (int p = 0; p < 8; ++p) {
    const int rr = sr + p * 16;
    float4 a = *(const float4*)(Aq + (size_t)(r0 + rr) * 64 + sk4);
    As[sk4+0][rr] = a.x; As[sk4+1][rr] = a.y; As[sk4+2][rr] = a.z; As[sk4+3][rr] = a.w;
  }
#pragma unroll
  for (int p = 0; p < 4; ++p) {
    const int rr = sr + p * 16;
    float4 b = *(const float4*)(Bk + (size_t)(c0 + rr) * 64 + sk4);
    Bs[sk4+0][rr] = b.x; Bs[sk4+1][rr] = b.y; Bs[sk4+2][rr] = b.z; Bs[sk4+3][rr] = b.w;
  }
  __syncthreads();
  const int ty = tid >> 4, tx = tid & 15;
  float acc[8][4] = {};
#pragma unroll 8
  for (int kk = 0; kk < 64; ++kk) {
    const float4 x0 = *(const float4*)&As[kk][ty * 8];
    const float4 x1 = *(const float4*)&As[kk][ty * 8 + 4];
    const float4 y  = *(const float4*)&Bs[kk][tx * 4];
    const float xa[8] = {x0.x, x0.y, x0.z, x0.w, x1.x, x1.y, x1.z, x1.w};
    const float yb[4] = {y.x, y.y, y.z, y.w};
#pragma unroll
    for (int i = 0; i < 8; ++i)
#pragma unroll
      for (int j = 0; j < 4; ++j)
        acc[i][j] = fmaf(xa[i], yb[j], acc[i][j]);
  }
  float* outp = attn + ((size_t)bh << 20);
#pragma unroll
  for (int i = 0; i < 8; ++i) {
    const int r = r0 + ty * 8 + i;
    float4 o = make_float4(acc[i][0] * INV_T, acc[i][1] * INV_T,
                           acc[i][2] * INV_T, acc[i][3] * INV_T);
    *(float4*)(outp + (size_t)r * 1024 + c0 + tx * 4) = o;
  }
}

// ---------------- kernel 3: softmax + top-6 sparsify + sparse PV -----------
// WAVE-synchronous: one 64-lane wave per row, 16 probs/lane, zero barriers.
__global__ __launch_bounds__(256) void sparse_row_kernel(
    float* __restrict__ attn, const float* __restrict__ vh,
    float* __restrict__ out_full)
{
  const int tid  = threadIdx.x;
  const int wv   = tid >> 6, lane = tid & 63;
  const int row  = blockIdx.x * 4 + wv;          // bh*1024 + lq
  const int bh   = row >> 10, lq = row & 1023;
  float* rp = attn + ((size_t)row << 10);
  __shared__ float s_w[4][8];
  __shared__ int   s_i[4][8];

  float p[16];
  {
    const float4 t0 = *(const float4*)(rp + lane * 4);
    const float4 t1 = *(const float4*)(rp + 256 + lane * 4);
    const float4 t2 = *(const float4*)(rp + 512 + lane * 4);
    const float4 t3 = *(const float4*)(rp + 768 + lane * 4);
    p[0]=t0.x; p[1]=t0.y; p[2]=t0.z; p[3]=t0.w;
    p[4]=t1.x; p[5]=t1.y; p[6]=t1.z; p[7]=t1.w;
    p[8]=t2.x; p[9]=t2.y; p[10]=t2.z; p[11]=t2.w;
    p[12]=t3.x; p[13]=t3.y; p[14]=t3.z; p[15]=t3.w;
  }

  float m = -1e30f;
#pragma unroll
  for (int j = 0; j < 16; ++j) m = fmaxf(m, p[j]);
  m = wred_max(m);
  float Z = 0.f;
#pragma unroll
  for (int j = 0; j < 16; ++j) { p[j] = __expf(p[j] - m); Z += p[j]; }
  Z = wred_sum(Z);
  const float invZ = 1.0f / Z;
#pragma unroll
  for (int j = 0; j < 16; ++j) p[j] *= invZ;

  // 6th largest with multiplicity: 5x (wave-max + remove one instance), then max
  unsigned rem = 0;
  float p6 = 0.f;
  for (int it = 0; it < 6; ++it) {
    float lm = -1.f;
#pragma unroll
    for (int j = 0; j < 16; ++j) if (!((rem >> j) & 1u)) lm = fmaxf(lm, p[j]);
    const float mm = wred_max(lm);
    if (it == 5) { p6 = mm; break; }
    const unsigned long long b = __ballot(lm == mm);
    if (lane == (__ffsll((long long)b) - 1)) {
      bool done = false;
#pragma unroll
      for (int j = 0; j < 16; ++j)
        if (!done && !((rem >> j) & 1u) && p[j] == mm) { rem |= (1u << j); done = true; }
    }
  }

  const float delta = p6 + SP_EPS;
  float w[16], lw = 0.f;
#pragma unroll
  for (int j = 0; j < 16; ++j) { w[j] = fmaxf(p[j] - delta, 0.f); lw += w[j]; }
  const float Wsum = wred_sum(lw);
  const float inv = 1.0f / (Wsum + SP_EPS);
#pragma unroll
  for (int j = 0; j < 16; ++j) w[j] *= inv;

  *(float4*)(rp +       lane * 4) = make_float4(w[0],  w[1],  w[2],  w[3]);
  *(float4*)(rp + 256 + lane * 4) = make_float4(w[4],  w[5],  w[6],  w[7]);
  *(float4*)(rp + 512 + lane * 4) = make_float4(w[8],  w[9],  w[10], w[11]);
  *(float4*)(rp + 768 + lane * 4) = make_float4(w[12], w[13], w[14], w[15]);

  int base = 0;
#pragma unroll
  for (int j = 0; j < 16; ++j) {
    const unsigned long long b = __ballot(w[j] > 0.f);
    if (w[j] > 0.f) {
      const int pos = base + __popcll(b & ((1ull << lane) - 1ull));
      if (pos < 8) { s_w[wv][pos] = w[j]; s_i[wv][pos] = (j >> 2) * 256 + lane * 4 + (j & 3); }
    }
    base += __popcll(b);
  }
  if (base > 8) base = 8;

  float acc = 0.f;
  const float* vb = vh + ((size_t)bh << 16);
  for (int t = 0; t < base; ++t)
    acc = fmaf(s_w[wv][t], vb[((size_t)s_i[wv][t] << 6) + lane], acc);
  const int b_ = bh & 3, h = bh >> 2;
  out_full[((size_t)((b_ << 10) | lq) << 9) + (h << 6) + lane] = acc;
}

// ---------------- kernel 4: fused fc+gate GEMMs + sigmoid*tanh epilogue ----
// 64x64 tile, BK=32, 3 LDS buffers, grid (64,8) = 512 blocks.
__global__ __launch_bounds__(256) void out_proj_fused_kernel(
    const float* __restrict__ A,
    const float* __restrict__ Wfc, const float* __restrict__ bfc,
    const float* __restrict__ Wg,  const float* __restrict__ bg,
    float* __restrict__ out)
{
  __shared__ float As[32][64];
  __shared__ float Bf[32][64];
  __shared__ float Bg[32][64];
  const int r0 = blockIdx.x * 64, n0 = blockIdx.y * 64;
  const int tid = threadIdx.x;
  const int lr = tid >> 2, lk8 = (tid & 3) * 8;
  const int ty = tid >> 4, tx = tid & 15;
  const int sa = (lk8 >> 3) & 1;
  float accf[4][4] = {}, accg[4][4] = {};
  for (int k0 = 0; k0 < 512; k0 += 32) {
    __syncthreads();
    const float4 a0 = *(const float4*)(A   + (size_t)(r0 + lr) * 512 + k0 + lk8);
    const float4 a1 = *(const float4*)(A   + (size_t)(r0 + lr) * 512 + k0 + lk8 + 4);
    const float4 f0 = *(const float4*)(Wfc + (size_t)(n0 + lr) * 512 + k0 + lk8);
    const float4 f1 = *(const float4*)(Wfc + (size_t)(n0 + lr) * 512 + k0 + lk8 + 4);
    const float4 g0 = *(const float4*)(Wg  + (size_t)(n0 + lr) * 512 + k0 + lk8);
    const float4 g1 = *(const float4*)(Wg  + (size_t)(n0 + lr) * 512 + k0 + lk8 + 4);
    const int c = lr ^ (sa << 4);
    As[lk8+0][c] = a0.x; As[lk8+1][c] = a0.y; As[lk8+2][c] = a0.z; As[lk8+3][c] = a0.w;
    As[lk8+4][c] = a1.x; As[lk8+5][c] = a1.y; As[lk8+6][c] = a1.z; As[lk8+7][c] = a1.w;
    Bf[lk8+0][c] = f0.x; Bf[lk8+1][c] = f0.y; Bf[lk8+2][c] = f0.z; Bf[lk8+3][c] = f0.w;
    Bf[lk8+4][c] = f1.x; Bf[lk8+5][c] = f1.y; Bf[lk8+6][c] = f1.z; Bf[lk8+7][c] = f1.w;
    Bg[lk8+0][c] = g0.x; Bg[lk8+1][c] = g0.y; Bg[lk8+2][c] = g0.z; Bg[lk8+3][c] = g0.w;
    Bg[lk8+4][c] = g1.x; Bg[lk8+5][c] = g1.y; Bg[lk8+6][c] = g1.z; Bg[lk8+7][c] = g1.w;
    __syncthreads();
#pragma unroll
    for (int kk = 0; kk < 32; ++kk) {
      const float4 x  = *(const float4*)&As[kk][swz(kk, ty * 4)];
      const float4 yf = *(const float4*)&Bf[kk][swz(kk, tx * 4)];
      const float4 yg = *(const float4*)&Bg[kk][swz(kk, tx * 4)];
      const float xa[4]  = {x.x, x.y, x.z, x.w};
      const float yfb[4] = {yf.x, yf.y, yf.z, yf.w};
      const float ygb[4] = {yg.x, yg.y, yg.z, yg.w};
#pragma unroll
      for (int i = 0; i < 4; ++i)
#pragma unroll
        for (int j = 0; j < 4; ++j) {
          accf[i][j] = fmaf(xa[i], yfb[j], accf[i][j]);
          accg[i][j] = fmaf(xa[i], ygb[j], accg[i][j]);
        }
    }
  }
  const int c = n0 + tx * 4;
  const float4 bf4 = *(const float4*)(bfc + c);
  const float4 bg4 = *(const float4*)(bg + c);
#pragma unroll
  for (int i = 0; i < 4; ++i) {
    const int r = r0 + ty * 4 + i;
    float4 o;
    o.x = tanhf(accf[i][0] + bf4.x) / (1.f + __expf(-(accg[i][0] + bg4.x)));
    o.y = tanhf(accf[i][1] + bf4.y) / (1.f + __expf(-(accg[i][1] + bg4.y)));
    o.z = tanhf(accf[i][2] + bf4.z) / (1.f + __expf(-(accg[i][2] + bg4.z)));
    o.w = tanhf(accf[i][3] + bf4.w) / (1.f + __expf(-(accg[i][3] + bg4.w)));
    *(float4*)(out + (size_t)r * 512 + c) = o;
  }
}

extern "C" void kernel_launch(void* const* d_in, const int* in_sizes, int n_in,
                              void* d_out, int out_size, void* d_ws, size_t ws_size,
                              hipStream_t stream) {
  const float* q   = (const float*)d_in[0];
  const float* k   = (const float*)d_in[1];
  const float* v   = (const float*)d_in[2];
  const float* Wq  = (const float*)d_in[3];
  const float* bq  = (const float*)d_in[4];
  const float* Wk  = (const float*)d_in[5];
  const float* bk  = (const float*)d_in[6];
  const float* Wv  = (const float*)d_in[7];
  const float* bv  = (const float*)d_in[8];
  const float* Wfc = (const float*)d_in[9];
  const float* bfc = (const float*)d_in[10];
  const float* Wg  = (const float*)d_in[11];
  const float* bg  = (const float*)d_in[12];

  float* out  = (float*)d_out;
  float* attn = out + OUT0;                 // (32,1024,1024) — score scratch then final
  float* ws   = (float*)d_ws;
  float* qh = ws;                           // 2M floats each
  float* kh = ws + (1u << 21);
  float* vh = ws + (2u << 21);
  float* out_full = qh;                     // overlay: qh dead after scores

  qkv_proj_kernel<<<dim3(64, 8, 3), 256, 0, stream>>>(q, k, v, Wq, bq, Wk, bk, Wv, bv, qh, kh, vh);
  scores_kernel<<<dim3(8, 16, 32), 256, 0, stream>>>(qh, kh, attn);
  sparse_row_kernel<<<dim3(8192), 256, 0, stream>>>(attn, vh, out_full);
  out_proj_fused_kernel<<<dim3(64, 8), 256, 0, stream>>>(out_full, Wfc, bfc, Wg, bg, out);
}

// Round 4
// 180.947 us; speedup vs baseline: 2.0219x; 1.4253x over previous
//
#include <hip/hip_runtime.h>
#include <hip/hip_bf16.h>
#include <math.h>

#define SEQ    1024
#define DMODEL 512
#define OUT0   2097152      // 4*1024*512 (output 0 size)
#define SP_EPS 1e-7f
#define INV_T  0.125f       // 1/sqrt(64)

typedef __attribute__((ext_vector_type(8))) short bf16x8;
typedef __attribute__((ext_vector_type(4))) float f32x4;

// ---------------- bf16 split helpers (RN-to-nearest-even) ------------------
__device__ __forceinline__ unsigned short f2bf(float f) {
  unsigned int b = __float_as_uint(f);
  return (unsigned short)((b + 0x7fffu + ((b >> 16) & 1u)) >> 16);
}
__device__ __forceinline__ float bf2f(unsigned short u) {
  return __uint_as_float(((unsigned int)u) << 16);
}

// ---------------- wave (64-lane) reduction helpers -------------------------
__device__ __forceinline__ float wred_max(float v) {
#pragma unroll
  for (int o = 32; o > 0; o >>= 1) v = fmaxf(v, __shfl_xor(v, o));
  return v;
}
__device__ __forceinline__ float wred_sum(float v) {
#pragma unroll
  for (int o = 32; o > 0; o >>= 1) v += __shfl_xor(v, o);
  return v;
}

// ---------------- kernel 0a: split-convert q,k,v,Wq,Wk,Wv ------------------
// hi/lo bf16 arrays into the attn-region scratch (dead before scores writes).
__global__ __launch_bounds__(256) void convert6_kernel(
    const float* __restrict__ q, const float* __restrict__ k, const float* __restrict__ v,
    const float* __restrict__ Wq, const float* __restrict__ Wk, const float* __restrict__ Wv,
    unsigned short* __restrict__ S16)
{
  const int z = blockIdx.z;
  const float* src = (z == 0) ? q : (z == 1) ? k : (z == 2) ? v
                   : (z == 3) ? Wq : (z == 4) ? Wk : Wv;
  const int n = (z < 3) ? (1 << 21) : (1 << 18);
  unsigned short* hi = (z < 3) ? (S16 + (size_t)z * (1u << 22))
                               : (S16 + (12u << 20) + (size_t)(z - 3) * (1u << 19));
  unsigned short* lo = hi + n;
  const int i = (blockIdx.x * 256 + threadIdx.x) * 4;
  if (i >= n) return;
  const float4 x = *(const float4*)(src + i);
  ushort4 h, l;
  h.x = f2bf(x.x); l.x = f2bf(x.x - bf2f(h.x));
  h.y = f2bf(x.y); l.y = f2bf(x.y - bf2f(h.y));
  h.z = f2bf(x.z); l.z = f2bf(x.z - bf2f(h.z));
  h.w = f2bf(x.w); l.w = f2bf(x.w - bf2f(h.w));
  *(ushort4*)(hi + i) = h;
  *(ushort4*)(lo + i) = l;
}

// ---------------- kernel 0b: split-convert Wfc, Wg (runs after scores) -----
__global__ __launch_bounds__(256) void convertW2_kernel(
    const float* __restrict__ Wfc, const float* __restrict__ Wg,
    unsigned short* __restrict__ W2)
{
  const int z = blockIdx.z;
  const float* src = z ? Wg : Wfc;
  unsigned short* hi = W2 + (size_t)z * (2u << 18);
  unsigned short* lo = hi + (1 << 18);
  const int i = (blockIdx.x * 256 + threadIdx.x) * 4;
  const float4 x = *(const float4*)(src + i);
  ushort4 h, l;
  h.x = f2bf(x.x); l.x = f2bf(x.x - bf2f(h.x));
  h.y = f2bf(x.y); l.y = f2bf(x.y - bf2f(h.y));
  h.z = f2bf(x.z); l.z = f2bf(x.z - bf2f(h.z));
  h.w = f2bf(x.w); l.w = f2bf(x.w - bf2f(h.w));
  *(ushort4*)(hi + i) = h;
  *(ushort4*)(lo + i) = l;
}

// ---------------- kernel 1: QKV projection via split-bf16 MFMA -------------
// BM=64, BN=128, BK=64; 4 waves (2x2), wave tile 32x64; 16x16x32 bf16 MFMA.
// LDS rows are 128B, XOR-swizzled: short_idx ^= (row&7)<<3 (G4 recipe).
__global__ __launch_bounds__(256) void qkv_mfma_kernel(
    const unsigned short* __restrict__ S16,
    const float* __restrict__ bq, const float* __restrict__ bk, const float* __restrict__ bv,
    float* __restrict__ qh, float* __restrict__ kh, float* __restrict__ vh)
{
  __shared__ short Ash[64 * 64], Asl[64 * 64];
  __shared__ short Bsh[128 * 64], Bsl[128 * 64];
  const int z = blockIdx.z;
  const unsigned short* Ah = S16 + (size_t)z * (1u << 22);
  const unsigned short* Al = Ah + (1u << 21);
  const unsigned short* Wh = S16 + (12u << 20) + (size_t)z * (1u << 19);
  const unsigned short* Wl = Wh + (1u << 18);
  const float* bias = (z == 0) ? bq : (z == 1) ? bk : bv;
  float* C = (z == 0) ? qh : (z == 1) ? kh : vh;
  const int r0 = blockIdx.x * 64, n0 = blockIdx.y * 128;
  const int tid = threadIdx.x, lane = tid & 63, w = tid >> 6;
  const int wr = w >> 1, wc = w & 1;
  const int l15 = lane & 15, l4 = lane >> 4;

  f32x4 acc[2][4];
#pragma unroll
  for (int a = 0; a < 2; ++a)
#pragma unroll
    for (int b = 0; b < 4; ++b) acc[a][b] = (f32x4){0.f, 0.f, 0.f, 0.f};

  for (int kt = 0; kt < 8; ++kt) {
    __syncthreads();
#pragma unroll
    for (int p = 0; p < 2; ++p) {
      const int c = tid + p * 256, row = c >> 3, k8 = (c & 7) * 8;
      const bf16x8 hv = *(const bf16x8*)(Ah + (size_t)(r0 + row) * 512 + kt * 64 + k8);
      const bf16x8 lv = *(const bf16x8*)(Al + (size_t)(r0 + row) * 512 + kt * 64 + k8);
      const int si = row * 64 + (k8 ^ ((row & 7) << 3));
      *(bf16x8*)&Ash[si] = hv; *(bf16x8*)&Asl[si] = lv;
    }
#pragma unroll
    for (int p = 0; p < 4; ++p) {
      const int c = tid + p * 256, row = c >> 3, k8 = (c & 7) * 8;
      const bf16x8 hv = *(const bf16x8*)(Wh + (size_t)(n0 + row) * 512 + kt * 64 + k8);
      const bf16x8 lv = *(const bf16x8*)(Wl + (size_t)(n0 + row) * 512 + kt * 64 + k8);
      const int si = row * 64 + (k8 ^ ((row & 7) << 3));
      *(bf16x8*)&Bsh[si] = hv; *(bf16x8*)&Bsl[si] = lv;
    }
    __syncthreads();
#pragma unroll
    for (int kf = 0; kf < 2; ++kf) {
      const int kb = kf * 32 + l4 * 8;
      bf16x8 ah[2], al2[2];
#pragma unroll
      for (int rb = 0; rb < 2; ++rb) {
        const int ar = wr * 32 + rb * 16 + l15;
        const int si = ar * 64 + (kb ^ ((ar & 7) << 3));
        ah[rb] = *(bf16x8*)&Ash[si]; al2[rb] = *(bf16x8*)&Asl[si];
      }
#pragma unroll
      for (int cb = 0; cb < 4; ++cb) {
        const int br = wc * 64 + cb * 16 + l15;
        const int si = br * 64 + (kb ^ ((br & 7) << 3));
        const bf16x8 bh = *(bf16x8*)&Bsh[si];
        const bf16x8 bl = *(bf16x8*)&Bsl[si];
#pragma unroll
        for (int rb = 0; rb < 2; ++rb) {
          acc[rb][cb] = __builtin_amdgcn_mfma_f32_16x16x32_bf16(al2[rb], bh, acc[rb][cb], 0, 0, 0);
          acc[rb][cb] = __builtin_amdgcn_mfma_f32_16x16x32_bf16(ah[rb], bl, acc[rb][cb], 0, 0, 0);
          acc[rb][cb] = __builtin_amdgcn_mfma_f32_16x16x32_bf16(ah[rb], bh, acc[rb][cb], 0, 0, 0);
        }
      }
    }
  }
  // epilogue: + bias, scatter to head-major [(h*4+b)][l][d]
#pragma unroll
  for (int cb = 0; cb < 4; ++cb) {
    const int col = n0 + wc * 64 + cb * 16 + l15;
    const float bia = bias[col];
    const int h = col >> 6, d = col & 63;
#pragma unroll
    for (int rb = 0; rb < 2; ++rb)
#pragma unroll
      for (int ri = 0; ri < 4; ++ri) {
        const int row = r0 + wr * 32 + rb * 16 + l4 * 4 + ri;
        const int b = row >> 10, ll = row & 1023;
        C[((size_t)(h * 4 + b) << 16) + (ll << 6) + d] = acc[rb][cb][ri] + bia;
      }
  }
}

// ---------------- kernel 2: scores = qh @ kh^T / sqrt(dk) (f32) ------------
__global__ __launch_bounds__(256) void scores_kernel(
    const float* __restrict__ qh, const float* __restrict__ kh,
    float* __restrict__ attn)
{
  __shared__ float As[64][128];
  __shared__ float Bs[64][64];
  const int bh = blockIdx.z;
  const int r0 = blockIdx.x * 128, c0 = blockIdx.y * 64;
  const float* Aq = qh + ((size_t)bh << 16);
  const float* Bk = kh + ((size_t)bh << 16);
  const int tid = threadIdx.x;
  const int sr = tid & 15, sk4 = (tid >> 4) * 4;
#pragma unroll
  for (int p = 0; p < 8; ++p) {
    const int rr = sr + p * 16;
    float4 a = *(const float4*)(Aq + (size_t)(r0 + rr) * 64 + sk4);
    As[sk4+0][rr] = a.x; As[sk4+1][rr] = a.y; As[sk4+2][rr] = a.z; As[sk4+3][rr] = a.w;
  }
#pragma unroll
  for (int p = 0; p < 4; ++p) {
    const int rr = sr + p * 16;
    float4 b = *(const float4*)(Bk + (size_t)(c0 + rr) * 64 + sk4);
    Bs[sk4+0][rr] = b.x; Bs[sk4+1][rr] = b.y; Bs[sk4+2][rr] = b.z; Bs[sk4+3][rr] = b.w;
  }
  __syncthreads();
  const int ty = tid >> 4, tx = tid & 15;
  float acc[8][4] = {};
#pragma unroll 8
  for (int kk = 0; kk < 64; ++kk) {
    const float4 x0 = *(const float4*)&As[kk][ty * 8];
    const float4 x1 = *(const float4*)&As[kk][ty * 8 + 4];
    const float4 y  = *(const float4*)&Bs[kk][tx * 4];
    const float xa[8] = {x0.x, x0.y, x0.z, x0.w, x1.x, x1.y, x1.z, x1.w};
    const float yb[4] = {y.x, y.y, y.z, y.w};
#pragma unroll
    for (int i = 0; i < 8; ++i)
#pragma unroll
      for (int j = 0; j < 4; ++j)
        acc[i][j] = fmaf(xa[i], yb[j], acc[i][j]);
  }
  float* outp = attn + ((size_t)bh << 20);
#pragma unroll
  for (int i = 0; i < 8; ++i) {
    const int r = r0 + ty * 8 + i;
    float4 o = make_float4(acc[i][0] * INV_T, acc[i][1] * INV_T,
                           acc[i][2] * INV_T, acc[i][3] * INV_T);
    *(float4*)(outp + (size_t)r * 1024 + c0 + tx * 4) = o;
  }
}

// ---------------- kernel 3: softmax + top-6 sparsify + sparse PV -----------
// Wave-synchronous; epilogue writes out_full as split hi/lo bf16 for out_proj.
__global__ __launch_bounds__(256) void sparse_row_kernel(
    float* __restrict__ attn, const float* __restrict__ vh,
    unsigned short* __restrict__ ofhi, unsigned short* __restrict__ oflo)
{
  const int tid  = threadIdx.x;
  const int wv   = tid >> 6, lane = tid & 63;
  const int row  = blockIdx.x * 4 + wv;          // bh*1024 + lq
  const int bh   = row >> 10, lq = row & 1023;
  float* rp = attn + ((size_t)row << 10);
  __shared__ float s_w[4][8];
  __shared__ int   s_i[4][8];

  float p[16];
  {
    const float4 t0 = *(const float4*)(rp + lane * 4);
    const float4 t1 = *(const float4*)(rp + 256 + lane * 4);
    const float4 t2 = *(const float4*)(rp + 512 + lane * 4);
    const float4 t3 = *(const float4*)(rp + 768 + lane * 4);
    p[0]=t0.x; p[1]=t0.y; p[2]=t0.z; p[3]=t0.w;
    p[4]=t1.x; p[5]=t1.y; p[6]=t1.z; p[7]=t1.w;
    p[8]=t2.x; p[9]=t2.y; p[10]=t2.z; p[11]=t2.w;
    p[12]=t3.x; p[13]=t3.y; p[14]=t3.z; p[15]=t3.w;
  }

  float m = -1e30f;
#pragma unroll
  for (int j = 0; j < 16; ++j) m = fmaxf(m, p[j]);
  m = wred_max(m);
  float Z = 0.f;
#pragma unroll
  for (int j = 0; j < 16; ++j) { p[j] = __expf(p[j] - m); Z += p[j]; }
  Z = wred_sum(Z);
  const float invZ = 1.0f / Z;
#pragma unroll
  for (int j = 0; j < 16; ++j) p[j] *= invZ;

  unsigned rem = 0;
  float p6 = 0.f;
  for (int it = 0; it < 6; ++it) {
    float lm = -1.f;
#pragma unroll
    for (int j = 0; j < 16; ++j) if (!((rem >> j) & 1u)) lm = fmaxf(lm, p[j]);
    const float mm = wred_max(lm);
    if (it == 5) { p6 = mm; break; }
    const unsigned long long b = __ballot(lm == mm);
    if (lane == (__ffsll((long long)b) - 1)) {
      bool done = false;
#pragma unroll
      for (int j = 0; j < 16; ++j)
        if (!done && !((rem >> j) & 1u) && p[j] == mm) { rem |= (1u << j); done = true; }
    }
  }

  const float delta = p6 + SP_EPS;
  float wv16[16], lw = 0.f;
#pragma unroll
  for (int j = 0; j < 16; ++j) { wv16[j] = fmaxf(p[j] - delta, 0.f); lw += wv16[j]; }
  const float Wsum = wred_sum(lw);
  const float inv = 1.0f / (Wsum + SP_EPS);
#pragma unroll
  for (int j = 0; j < 16; ++j) wv16[j] *= inv;

  *(float4*)(rp +       lane * 4) = make_float4(wv16[0],  wv16[1],  wv16[2],  wv16[3]);
  *(float4*)(rp + 256 + lane * 4) = make_float4(wv16[4],  wv16[5],  wv16[6],  wv16[7]);
  *(float4*)(rp + 512 + lane * 4) = make_float4(wv16[8],  wv16[9],  wv16[10], wv16[11]);
  *(float4*)(rp + 768 + lane * 4) = make_float4(wv16[12], wv16[13], wv16[14], wv16[15]);

  int base = 0;
#pragma unroll
  for (int j = 0; j < 16; ++j) {
    const unsigned long long b = __ballot(wv16[j] > 0.f);
    if (wv16[j] > 0.f) {
      const int pos = base + __popcll(b & ((1ull << lane) - 1ull));
      if (pos < 8) { s_w[wv][pos] = wv16[j]; s_i[wv][pos] = (j >> 2) * 256 + lane * 4 + (j & 3); }
    }
    base += __popcll(b);
  }
  if (base > 8) base = 8;

  float acc = 0.f;
  const float* vb = vh + ((size_t)bh << 16);
  for (int t = 0; t < base; ++t)
    acc = fmaf(s_w[wv][t], vb[((size_t)s_i[wv][t] << 6) + lane], acc);
  const int b_ = bh & 3, h = bh >> 2;
  const int idx = (((b_ << 10) | lq) << 9) + (h << 6) + lane;
  const unsigned short hv = f2bf(acc);
  ofhi[idx] = hv;
  oflo[idx] = f2bf(acc - bf2f(hv));
}

// ---------------- kernel 4: fc+gate via split-bf16 MFMA + fused epilogue ---
// BM=64, BN=128 (of each of Wfc/Wg), BK=64; both GEMMs in one block.
__global__ __launch_bounds__(256) void out_proj_mfma_kernel(
    const unsigned short* __restrict__ Ahl, const unsigned short* __restrict__ W2,
    const float* __restrict__ bfc, const float* __restrict__ bg,
    float* __restrict__ out)
{
  __shared__ short Ash[64 * 64], Asl[64 * 64];
  __shared__ short Bfh[128 * 64], Bfl[128 * 64];
  __shared__ short Bgh[128 * 64], Bgl[128 * 64];
  const unsigned short* Ah  = Ahl;
  const unsigned short* Al  = Ahl + (1u << 21);
  const unsigned short* Wfh = W2;
  const unsigned short* Wfl = W2 + (1u << 18);
  const unsigned short* Wgh = W2 + (2u << 18);
  const unsigned short* Wgl = W2 + 3u * (1u << 18);
  const int r0 = blockIdx.x * 64, n0 = blockIdx.y * 128;
  const int tid = threadIdx.x, lane = tid & 63, w = tid >> 6;
  const int wr = w >> 1, wc = w & 1;
  const int l15 = lane & 15, l4 = lane >> 4;

  f32x4 accf[2][4], accg[2][4];
#pragma unroll
  for (int a = 0; a < 2; ++a)
#pragma unroll
    for (int b = 0; b < 4; ++b) {
      accf[a][b] = (f32x4){0.f, 0.f, 0.f, 0.f};
      accg[a][b] = (f32x4){0.f, 0.f, 0.f, 0.f};
    }

  for (int kt = 0; kt < 8; ++kt) {
    __syncthreads();
#pragma unroll
    for (int p = 0; p < 2; ++p) {
      const int c = tid + p * 256, row = c >> 3, k8 = (c & 7) * 8;
      const bf16x8 hv = *(const bf16x8*)(Ah + (size_t)(r0 + row) * 512 + kt * 64 + k8);
      const bf16x8 lv = *(const bf16x8*)(Al + (size_t)(r0 + row) * 512 + kt * 64 + k8);
      const int si = row * 64 + (k8 ^ ((row & 7) << 3));
      *(bf16x8*)&Ash[si] = hv; *(bf16x8*)&Asl[si] = lv;
    }
#pragma unroll
    for (int p = 0; p < 4; ++p) {
      const int c = tid + p * 256, row = c >> 3, k8 = (c & 7) * 8;
      const int si = row * 64 + (k8 ^ ((row & 7) << 3));
      const size_t go = (size_t)(n0 + row) * 512 + kt * 64 + k8;
      *(bf16x8*)&Bfh[si] = *(const bf16x8*)(Wfh + go);
      *(bf16x8*)&Bfl[si] = *(const bf16x8*)(Wfl + go);
      *(bf16x8*)&Bgh[si] = *(const bf16x8*)(Wgh + go);
      *(bf16x8*)&Bgl[si] = *(const bf16x8*)(Wgl + go);
    }
    __syncthreads();
#pragma unroll
    for (int kf = 0; kf < 2; ++kf) {
      const int kb = kf * 32 + l4 * 8;
      bf16x8 ah[2], al2[2];
#pragma unroll
      for (int rb = 0; rb < 2; ++rb) {
        const int ar = wr * 32 + rb * 16 + l15;
        const int si = ar * 64 + (kb ^ ((ar & 7) << 3));
        ah[rb] = *(bf16x8*)&Ash[si]; al2[rb] = *(bf16x8*)&Asl[si];
      }
#pragma unroll
      for (int cb = 0; cb < 4; ++cb) {
        const int br = wc * 64 + cb * 16 + l15;
        const int si = br * 64 + (kb ^ ((br & 7) << 3));
        const bf16x8 fh = *(bf16x8*)&Bfh[si];
        const bf16x8 fl = *(bf16x8*)&Bfl[si];
        const bf16x8 gh = *(bf16x8*)&Bgh[si];
        const bf16x8 gl = *(bf16x8*)&Bgl[si];
#pragma unroll
        for (int rb = 0; rb < 2; ++rb) {
          accf[rb][cb] = __builtin_amdgcn_mfma_f32_16x16x32_bf16(al2[rb], fh, accf[rb][cb], 0, 0, 0);
          accf[rb][cb] = __builtin_amdgcn_mfma_f32_16x16x32_bf16(ah[rb], fl, accf[rb][cb], 0, 0, 0);
          accf[rb][cb] = __builtin_amdgcn_mfma_f32_16x16x32_bf16(ah[rb], fh, accf[rb][cb], 0, 0, 0);
          accg[rb][cb] = __builtin_amdgcn_mfma_f32_16x16x32_bf16(al2[rb], gh, accg[rb][cb], 0, 0, 0);
          accg[rb][cb] = __builtin_amdgcn_mfma_f32_16x16x32_bf16(ah[rb], gl, accg[rb][cb], 0, 0, 0);
          accg[rb][cb] = __builtin_amdgcn_mfma_f32_16x16x32_bf16(ah[rb], gh, accg[rb][cb], 0, 0, 0);
        }
      }
    }
  }
#pragma unroll
  for (int cb = 0; cb < 4; ++cb) {
    const int col = n0 + wc * 64 + cb * 16 + l15;
    const float bf4 = bfc[col];
    const float bg4 = bg[col];
#pragma unroll
    for (int rb = 0; rb < 2; ++rb)
#pragma unroll
      for (int ri = 0; ri < 4; ++ri) {
        const int row = r0 + wr * 32 + rb * 16 + l4 * 4 + ri;
        const float f = accf[rb][cb][ri] + bf4;
        const float g = accg[rb][cb][ri] + bg4;
        out[(size_t)row * 512 + col] = tanhf(f) / (1.f + __expf(-g));
      }
  }
}

extern "C" void kernel_launch(void* const* d_in, const int* in_sizes, int n_in,
                              void* d_out, int out_size, void* d_ws, size_t ws_size,
                              hipStream_t stream) {
  const float* q   = (const float*)d_in[0];
  const float* k   = (const float*)d_in[1];
  const float* v   = (const float*)d_in[2];
  const float* Wq  = (const float*)d_in[3];
  const float* bq  = (const float*)d_in[4];
  const float* Wk  = (const float*)d_in[5];
  const float* bk  = (const float*)d_in[6];
  const float* Wv  = (const float*)d_in[7];
  const float* bv  = (const float*)d_in[8];
  const float* Wfc = (const float*)d_in[9];
  const float* bfc = (const float*)d_in[10];
  const float* Wg  = (const float*)d_in[11];
  const float* bg  = (const float*)d_in[12];

  float* out  = (float*)d_out;
  float* attn = out + OUT0;                     // (32,1024,1024) final output 1
  unsigned short* S16 = (unsigned short*)attn;  // split scratch, dead before scores
  float* ws   = (float*)d_ws;
  float* qh = ws;                               // 2M floats each
  float* kh = ws + (1u << 21);
  float* vh = ws + (2u << 21);
  unsigned short* ofhl = (unsigned short*)ws;            // overlay qh: out_full hi[2M], lo[2M]
  unsigned short* W2   = (unsigned short*)(ws + (1u << 21)); // overlay kh: Wfc/Wg splits (1M ushorts)

  convert6_kernel<<<dim3(2048, 1, 6), 256, 0, stream>>>(q, k, v, Wq, Wk, Wv, S16);
  qkv_mfma_kernel<<<dim3(64, 4, 3), 256, 0, stream>>>(S16, bq, bk, bv, qh, kh, vh);
  scores_kernel<<<dim3(8, 16, 32), 256, 0, stream>>>(qh, kh, attn);
  convertW2_kernel<<<dim3(256, 1, 2), 256, 0, stream>>>(Wfc, Wg, W2);
  sparse_row_kernel<<<dim3(8192), 256, 0, stream>>>(attn, vh, ofhl, ofhl + (1u << 21));
  out_proj_mfma_kernel<<<dim3(64, 4), 256, 0, stream>>>(ofhl, W2, bfc, bg, out);
}

// Round 5
// 141.765 us; speedup vs baseline: 2.5807x; 1.2764x over previous
//
#include <hip/hip_runtime.h>
#include <hip/hip_bf16.h>
#include <math.h>

#define SEQ    1024
#define DMODEL 512
#define OUT0   2097152      // 4*1024*512 (output 0 size)
#define SP_EPS 1e-7f
#define INV_T  0.125f       // 1/sqrt(64)

typedef __attribute__((ext_vector_type(8))) short bf16x8;
typedef __attribute__((ext_vector_type(4))) float f32x4;

// ---------------- bf16 split helpers (RN-to-nearest-even) ------------------
__device__ __forceinline__ unsigned short f2bf(float f) {
  unsigned int b = __float_as_uint(f);
  return (unsigned short)((b + 0x7fffu + ((b >> 16) & 1u)) >> 16);
}
__device__ __forceinline__ float bf2f(unsigned short u) {
  return __uint_as_float(((unsigned int)u) << 16);
}

// ---------------- wave (64-lane) reduction helpers -------------------------
__device__ __forceinline__ float wred_max(float v) {
#pragma unroll
  for (int o = 32; o > 0; o >>= 1) v = fmaxf(v, __shfl_xor(v, o));
  return v;
}
__device__ __forceinline__ float wred_sum(float v) {
#pragma unroll
  for (int o = 32; o > 0; o >>= 1) v += __shfl_xor(v, o);
  return v;
}

// ---------------- kernel 0a: split-convert q,k,v,Wq,Wk,Wv ------------------
__global__ __launch_bounds__(256) void convert6_kernel(
    const float* __restrict__ q, const float* __restrict__ k, const float* __restrict__ v,
    const float* __restrict__ Wq, const float* __restrict__ Wk, const float* __restrict__ Wv,
    unsigned short* __restrict__ S16)
{
  const int z = blockIdx.z;
  const float* src = (z == 0) ? q : (z == 1) ? k : (z == 2) ? v
                   : (z == 3) ? Wq : (z == 4) ? Wk : Wv;
  const int n = (z < 3) ? (1 << 21) : (1 << 18);
  unsigned short* hi = (z < 3) ? (S16 + (size_t)z * (1u << 22))
                               : (S16 + (12u << 20) + (size_t)(z - 3) * (1u << 19));
  unsigned short* lo = hi + n;
  const int i = (blockIdx.x * 256 + threadIdx.x) * 4;
  if (i >= n) return;
  const float4 x = *(const float4*)(src + i);
  ushort4 h, l;
  h.x = f2bf(x.x); l.x = f2bf(x.x - bf2f(h.x));
  h.y = f2bf(x.y); l.y = f2bf(x.y - bf2f(h.y));
  h.z = f2bf(x.z); l.z = f2bf(x.z - bf2f(h.z));
  h.w = f2bf(x.w); l.w = f2bf(x.w - bf2f(h.w));
  *(ushort4*)(hi + i) = h;
  *(ushort4*)(lo + i) = l;
}

// ---------------- kernel 0b: split-convert Wfc, Wg -------------------------
__global__ __launch_bounds__(256) void convertW2_kernel(
    const float* __restrict__ Wfc, const float* __restrict__ Wg,
    unsigned short* __restrict__ W2)
{
  const int z = blockIdx.z;
  const float* src = z ? Wg : Wfc;
  unsigned short* hi = W2 + (size_t)z * (2u << 18);
  unsigned short* lo = hi + (1 << 18);
  const int i = (blockIdx.x * 256 + threadIdx.x) * 4;
  const float4 x = *(const float4*)(src + i);
  ushort4 h, l;
  h.x = f2bf(x.x); l.x = f2bf(x.x - bf2f(h.x));
  h.y = f2bf(x.y); l.y = f2bf(x.y - bf2f(h.y));
  h.z = f2bf(x.z); l.z = f2bf(x.z - bf2f(h.z));
  h.w = f2bf(x.w); l.w = f2bf(x.w - bf2f(h.w));
  *(ushort4*)(hi + i) = h;
  *(ushort4*)(lo + i) = l;
}

// ---------------- kernel 1: QKV projection via split-bf16 MFMA -------------
// BM=64, BN=128, BK=64; 4 waves (2x2). q,k outputs written as hi/lo bf16
// split (for the MFMA scores kernel); v output stays f32 (for sparse PV).
__global__ __launch_bounds__(256) void qkv_mfma_kernel(
    const unsigned short* __restrict__ S16,
    const float* __restrict__ bq, const float* __restrict__ bk, const float* __restrict__ bv,
    unsigned short* __restrict__ qhh, unsigned short* __restrict__ qhl,
    unsigned short* __restrict__ khh, unsigned short* __restrict__ khl,
    float* __restrict__ vh)
{
  __shared__ short Ash[64 * 64], Asl[64 * 64];
  __shared__ short Bsh[128 * 64], Bsl[128 * 64];
  const int z = blockIdx.z;
  const unsigned short* Ah = S16 + (size_t)z * (1u << 22);
  const unsigned short* Al = Ah + (1u << 21);
  const unsigned short* Wh = S16 + (12u << 20) + (size_t)z * (1u << 19);
  const unsigned short* Wl = Wh + (1u << 18);
  const float* bias = (z == 0) ? bq : (z == 1) ? bk : bv;
  const int r0 = blockIdx.x * 64, n0 = blockIdx.y * 128;
  const int tid = threadIdx.x, lane = tid & 63, w = tid >> 6;
  const int wr = w >> 1, wc = w & 1;
  const int l15 = lane & 15, l4 = lane >> 4;

  f32x4 acc[2][4];
#pragma unroll
  for (int a = 0; a < 2; ++a)
#pragma unroll
    for (int b = 0; b < 4; ++b) acc[a][b] = (f32x4){0.f, 0.f, 0.f, 0.f};

  for (int kt = 0; kt < 8; ++kt) {
    __syncthreads();
#pragma unroll
    for (int p = 0; p < 2; ++p) {
      const int c = tid + p * 256, row = c >> 3, k8 = (c & 7) * 8;
      const bf16x8 hv = *(const bf16x8*)(Ah + (size_t)(r0 + row) * 512 + kt * 64 + k8);
      const bf16x8 lv = *(const bf16x8*)(Al + (size_t)(r0 + row) * 512 + kt * 64 + k8);
      const int si = row * 64 + (k8 ^ ((row & 7) << 3));
      *(bf16x8*)&Ash[si] = hv; *(bf16x8*)&Asl[si] = lv;
    }
#pragma unroll
    for (int p = 0; p < 4; ++p) {
      const int c = tid + p * 256, row = c >> 3, k8 = (c & 7) * 8;
      const bf16x8 hv = *(const bf16x8*)(Wh + (size_t)(n0 + row) * 512 + kt * 64 + k8);
      const bf16x8 lv = *(const bf16x8*)(Wl + (size_t)(n0 + row) * 512 + kt * 64 + k8);
      const int si = row * 64 + (k8 ^ ((row & 7) << 3));
      *(bf16x8*)&Bsh[si] = hv; *(bf16x8*)&Bsl[si] = lv;
    }
    __syncthreads();
#pragma unroll
    for (int kf = 0; kf < 2; ++kf) {
      const int kb = kf * 32 + l4 * 8;
      bf16x8 ah[2], al2[2];
#pragma unroll
      for (int rb = 0; rb < 2; ++rb) {
        const int ar = wr * 32 + rb * 16 + l15;
        const int si = ar * 64 + (kb ^ ((ar & 7) << 3));
        ah[rb] = *(bf16x8*)&Ash[si]; al2[rb] = *(bf16x8*)&Asl[si];
      }
#pragma unroll
      for (int cb = 0; cb < 4; ++cb) {
        const int br = wc * 64 + cb * 16 + l15;
        const int si = br * 64 + (kb ^ ((br & 7) << 3));
        const bf16x8 bh = *(bf16x8*)&Bsh[si];
        const bf16x8 bl = *(bf16x8*)&Bsl[si];
#pragma unroll
        for (int rb = 0; rb < 2; ++rb) {
          acc[rb][cb] = __builtin_amdgcn_mfma_f32_16x16x32_bf16(al2[rb], bh, acc[rb][cb], 0, 0, 0);
          acc[rb][cb] = __builtin_amdgcn_mfma_f32_16x16x32_bf16(ah[rb], bl, acc[rb][cb], 0, 0, 0);
          acc[rb][cb] = __builtin_amdgcn_mfma_f32_16x16x32_bf16(ah[rb], bh, acc[rb][cb], 0, 0, 0);
        }
      }
    }
  }
  unsigned short* H = (z == 0) ? qhh : khh;
  unsigned short* L = (z == 0) ? qhl : khl;
#pragma unroll
  for (int cb = 0; cb < 4; ++cb) {
    const int col = n0 + wc * 64 + cb * 16 + l15;
    const float bia = bias[col];
    const int h = col >> 6, d = col & 63;
#pragma unroll
    for (int rb = 0; rb < 2; ++rb)
#pragma unroll
      for (int ri = 0; ri < 4; ++ri) {
        const int row = r0 + wr * 32 + rb * 16 + l4 * 4 + ri;
        const int b = row >> 10, ll = row & 1023;
        const size_t idx = ((size_t)(h * 4 + b) << 16) + (ll << 6) + d;
        const float val = acc[rb][cb][ri] + bia;
        if (z == 2) {
          vh[idx] = val;
        } else {
          const unsigned short hv = f2bf(val);
          H[idx] = hv;
          L[idx] = f2bf(val - bf2f(hv));
        }
      }
  }
}

// ---------------- kernel 2: scores via split-bf16 MFMA ---------------------
// per bh: Q(1024x64) @ K(1024x64)^T / 8; BM=BN=64, K=64, 4 waves 2x2.
__global__ __launch_bounds__(256) void scores_mfma_kernel(
    const unsigned short* __restrict__ qhh, const unsigned short* __restrict__ qhl,
    const unsigned short* __restrict__ khh, const unsigned short* __restrict__ khl,
    float* __restrict__ attn)
{
  __shared__ short Qh[64 * 64], Ql[64 * 64], Kh[64 * 64], Kl[64 * 64];
  const int bh = blockIdx.z;
  const int r0 = blockIdx.x * 64, c0 = blockIdx.y * 64;
  const int tid = threadIdx.x, lane = tid & 63, w = tid >> 6;
  const int wr = w >> 1, wc = w & 1;
  const int l15 = lane & 15, l4 = lane >> 4;
  const size_t base = (size_t)bh << 16;
#pragma unroll
  for (int p = 0; p < 2; ++p) {
    const int c = tid + p * 256, row = c >> 3, k8 = (c & 7) * 8;
    const int si = row * 64 + (k8 ^ ((row & 7) << 3));
    *(bf16x8*)&Qh[si] = *(const bf16x8*)(qhh + base + (size_t)(r0 + row) * 64 + k8);
    *(bf16x8*)&Ql[si] = *(const bf16x8*)(qhl + base + (size_t)(r0 + row) * 64 + k8);
    *(bf16x8*)&Kh[si] = *(const bf16x8*)(khh + base + (size_t)(c0 + row) * 64 + k8);
    *(bf16x8*)&Kl[si] = *(const bf16x8*)(khl + base + (size_t)(c0 + row) * 64 + k8);
  }
  __syncthreads();
  f32x4 acc[2][2];
#pragma unroll
  for (int a = 0; a < 2; ++a)
#pragma unroll
    for (int b = 0; b < 2; ++b) acc[a][b] = (f32x4){0.f, 0.f, 0.f, 0.f};
#pragma unroll
  for (int kf = 0; kf < 2; ++kf) {
    const int kb = kf * 32 + l4 * 8;
    bf16x8 ah[2], al2[2];
#pragma unroll
    for (int rb = 0; rb < 2; ++rb) {
      const int ar = wr * 32 + rb * 16 + l15;
      const int si = ar * 64 + (kb ^ ((ar & 7) << 3));
      ah[rb] = *(bf16x8*)&Qh[si]; al2[rb] = *(bf16x8*)&Ql[si];
    }
#pragma unroll
    for (int cb = 0; cb < 2; ++cb) {
      const int br = wc * 32 + cb * 16 + l15;
      const int si = br * 64 + (kb ^ ((br & 7) << 3));
      const bf16x8 bh8 = *(bf16x8*)&Kh[si];
      const bf16x8 bl8 = *(bf16x8*)&Kl[si];
#pragma unroll
      for (int rb = 0; rb < 2; ++rb) {
        acc[rb][cb] = __builtin_amdgcn_mfma_f32_16x16x32_bf16(al2[rb], bh8, acc[rb][cb], 0, 0, 0);
        acc[rb][cb] = __builtin_amdgcn_mfma_f32_16x16x32_bf16(ah[rb], bl8, acc[rb][cb], 0, 0, 0);
        acc[rb][cb] = __builtin_amdgcn_mfma_f32_16x16x32_bf16(ah[rb], bh8, acc[rb][cb], 0, 0, 0);
      }
    }
  }
  float* outp = attn + ((size_t)bh << 20);
#pragma unroll
  for (int cb = 0; cb < 2; ++cb) {
    const int col = c0 + wc * 32 + cb * 16 + l15;
#pragma unroll
    for (int rb = 0; rb < 2; ++rb)
#pragma unroll
      for (int ri = 0; ri < 4; ++ri) {
        const int row = r0 + wr * 32 + rb * 16 + l4 * 4 + ri;
        outp[(size_t)row * 1024 + col] = acc[rb][cb][ri] * INV_T;
      }
  }
}

// ---------------- kernel 3: softmax + top-6 sparsify + sparse PV -----------
// Wave-synchronous, branch-free top-6: unnormalized exp-space, lane-local
// sorted top-6 (insertion network) + 6-step shfl_xor bitonic list merge.
__global__ __launch_bounds__(256) void sparse_row_kernel(
    float* __restrict__ attn, const float* __restrict__ vh,
    unsigned short* __restrict__ ofhi, unsigned short* __restrict__ oflo)
{
  const int tid  = threadIdx.x;
  const int wv   = tid >> 6, lane = tid & 63;
  const int row  = blockIdx.x * 4 + wv;          // bh*1024 + lq
  const int bh   = row >> 10, lq = row & 1023;
  float* rp = attn + ((size_t)row << 10);
  __shared__ float s_w[4][8];
  __shared__ int   s_i[4][8];

  float u[16];
  {
    const float4 t0 = *(const float4*)(rp + lane * 4);
    const float4 t1 = *(const float4*)(rp + 256 + lane * 4);
    const float4 t2 = *(const float4*)(rp + 512 + lane * 4);
    const float4 t3 = *(const float4*)(rp + 768 + lane * 4);
    u[0]=t0.x; u[1]=t0.y; u[2]=t0.z; u[3]=t0.w;
    u[4]=t1.x; u[5]=t1.y; u[6]=t1.z; u[7]=t1.w;
    u[8]=t2.x; u[9]=t2.y; u[10]=t2.z; u[11]=t2.w;
    u[12]=t3.x; u[13]=t3.y; u[14]=t3.z; u[15]=t3.w;
  }

  float m = -1e30f;
#pragma unroll
  for (int j = 0; j < 16; ++j) m = fmaxf(m, u[j]);
  m = wred_max(m);
  float Zl = 0.f;
#pragma unroll
  for (int j = 0; j < 16; ++j) { u[j] = __expf(u[j] - m); Zl += u[j]; }
  const float Z = wred_sum(Zl);

  // lane-local top-6 sorted desc (insertion network, uniform)
  float t0 = -1e30f, t1 = -1e30f, t2 = -1e30f, t3 = -1e30f, t4 = -1e30f, t5 = -1e30f;
#pragma unroll
  for (int j = 0; j < 16; ++j) {
    float v = u[j], a;
    a = fmaxf(t0, v); v = fminf(t0, v); t0 = a;
    a = fmaxf(t1, v); v = fminf(t1, v); t1 = a;
    a = fmaxf(t2, v); v = fminf(t2, v); t2 = a;
    a = fmaxf(t3, v); v = fminf(t3, v); t3 = a;
    a = fmaxf(t4, v); v = fminf(t4, v); t4 = a;
    t5 = fmaxf(t5, v);
  }
  // butterfly merge of sorted-6 lists: half-cleaner max + dist-3 + 2x sort3
#pragma unroll
  for (int off = 1; off < 64; off <<= 1) {
    const float b0 = __shfl_xor(t0, off), b1 = __shfl_xor(t1, off),
                b2 = __shfl_xor(t2, off), b3 = __shfl_xor(t3, off),
                b4 = __shfl_xor(t4, off), b5 = __shfl_xor(t5, off);
    float m0 = fmaxf(t0, b5), m1 = fmaxf(t1, b4), m2 = fmaxf(t2, b3),
          m3 = fmaxf(t3, b2), m4 = fmaxf(t4, b1), m5 = fmaxf(t5, b0);
    float a;
    a = fmaxf(m0, m3); m3 = fminf(m0, m3); m0 = a;   // dist-3 half-cleaner
    a = fmaxf(m1, m4); m4 = fminf(m1, m4); m1 = a;
    a = fmaxf(m2, m5); m5 = fminf(m2, m5); m2 = a;
    a = fmaxf(m0, m1); m1 = fminf(m0, m1); m0 = a;   // sort3 upper
    a = fmaxf(m0, m2); m2 = fminf(m0, m2); m0 = a;
    a = fmaxf(m1, m2); m2 = fminf(m1, m2); m1 = a;
    a = fmaxf(m3, m4); m4 = fminf(m3, m4); m3 = a;   // sort3 lower
    a = fmaxf(m3, m5); m5 = fminf(m3, m5); m3 = a;
    a = fmaxf(m4, m5); m5 = fminf(m4, m5); m4 = a;
    t0 = m0; t1 = m1; t2 = m2; t3 = m3; t4 = m4; t5 = m5;
  }

  // unnormalized threshold: du/Z == attn6 + EPS exactly
  const float du = t5 + SP_EPS * Z;
  float w[16], Sl = 0.f;
#pragma unroll
  for (int j = 0; j < 16; ++j) { w[j] = fmaxf(u[j] - du, 0.f); Sl += w[j]; }
  const float S = wred_sum(Sl);
  const float inv = 1.0f / (S + SP_EPS * Z);
#pragma unroll
  for (int j = 0; j < 16; ++j) w[j] *= inv;

  *(float4*)(rp +       lane * 4) = make_float4(w[0],  w[1],  w[2],  w[3]);
  *(float4*)(rp + 256 + lane * 4) = make_float4(w[4],  w[5],  w[6],  w[7]);
  *(float4*)(rp + 512 + lane * 4) = make_float4(w[8],  w[9],  w[10], w[11]);
  *(float4*)(rp + 768 + lane * 4) = make_float4(w[12], w[13], w[14], w[15]);

  int base = 0;
#pragma unroll
  for (int j = 0; j < 16; ++j) {
    const unsigned long long b = __ballot(w[j] > 0.f);
    if (w[j] > 0.f) {
      const int pos = base + __popcll(b & ((1ull << lane) - 1ull));
      if (pos < 8) { s_w[wv][pos] = w[j]; s_i[wv][pos] = (j >> 2) * 256 + lane * 4 + (j & 3); }
    }
    base += __popcll(b);
  }
  if (base > 8) base = 8;

  float acc = 0.f;
  const float* vb = vh + ((size_t)bh << 16);
  for (int t = 0; t < base; ++t)
    acc = fmaf(s_w[wv][t], vb[((size_t)s_i[wv][t] << 6) + lane], acc);
  const int b_ = bh & 3, h = bh >> 2;
  const int idx = (((b_ << 10) | lq) << 9) + (h << 6) + lane;
  const unsigned short hv = f2bf(acc);
  ofhi[idx] = hv;
  oflo[idx] = f2bf(acc - bf2f(hv));
}

// ---------------- kernel 4: fc+gate via split-bf16 MFMA + fused epilogue ---
__global__ __launch_bounds__(256) void out_proj_mfma_kernel(
    const unsigned short* __restrict__ Ahl, const unsigned short* __restrict__ W2,
    const float* __restrict__ bfc, const float* __restrict__ bg,
    float* __restrict__ out)
{
  __shared__ short Ash[64 * 64], Asl[64 * 64];
  __shared__ short Bfh[128 * 64], Bfl[128 * 64];
  __shared__ short Bgh[128 * 64], Bgl[128 * 64];
  const unsigned short* Ah  = Ahl;
  const unsigned short* Al  = Ahl + (1u << 21);
  const unsigned short* Wfh = W2;
  const unsigned short* Wfl = W2 + (1u << 18);
  const unsigned short* Wgh = W2 + (2u << 18);
  const unsigned short* Wgl = W2 + 3u * (1u << 18);
  const int r0 = blockIdx.x * 64, n0 = blockIdx.y * 128;
  const int tid = threadIdx.x, lane = tid & 63, w = tid >> 6;
  const int wr = w >> 1, wc = w & 1;
  const int l15 = lane & 15, l4 = lane >> 4;

  f32x4 accf[2][4], accg[2][4];
#pragma unroll
  for (int a = 0; a < 2; ++a)
#pragma unroll
    for (int b = 0; b < 4; ++b) {
      accf[a][b] = (f32x4){0.f, 0.f, 0.f, 0.f};
      accg[a][b] = (f32x4){0.f, 0.f, 0.f, 0.f};
    }

  for (int kt = 0; kt < 8; ++kt) {
    __syncthreads();
#pragma unroll
    for (int p = 0; p < 2; ++p) {
      const int c = tid + p * 256, row = c >> 3, k8 = (c & 7) * 8;
      const bf16x8 hv = *(const bf16x8*)(Ah + (size_t)(r0 + row) * 512 + kt * 64 + k8);
      const bf16x8 lv = *(const bf16x8*)(Al + (size_t)(r0 + row) * 512 + kt * 64 + k8);
      const int si = row * 64 + (k8 ^ ((row & 7) << 3));
      *(bf16x8*)&Ash[si] = hv; *(bf16x8*)&Asl[si] = lv;
    }
#pragma unroll
    for (int p = 0; p < 4; ++p) {
      const int c = tid + p * 256, row = c >> 3, k8 = (c & 7) * 8;
      const int si = row * 64 + (k8 ^ ((row & 7) << 3));
      const size_t go = (size_t)(n0 + row) * 512 + kt * 64 + k8;
      *(bf16x8*)&Bfh[si] = *(const bf16x8*)(Wfh + go);
      *(bf16x8*)&Bfl[si] = *(const bf16x8*)(Wfl + go);
      *(bf16x8*)&Bgh[si] = *(const bf16x8*)(Wgh + go);
      *(bf16x8*)&Bgl[si] = *(const bf16x8*)(Wgl + go);
    }
    __syncthreads();
#pragma unroll
    for (int kf = 0; kf < 2; ++kf) {
      const int kb = kf * 32 + l4 * 8;
      bf16x8 ah[2], al2[2];
#pragma unroll
      for (int rb = 0; rb < 2; ++rb) {
        const int ar = wr * 32 + rb * 16 + l15;
        const int si = ar * 64 + (kb ^ ((ar & 7) << 3));
        ah[rb] = *(bf16x8*)&Ash[si]; al2[rb] = *(bf16x8*)&Asl[si];
      }
#pragma unroll
      for (int cb = 0; cb < 4; ++cb) {
        const int br = wc * 64 + cb * 16 + l15;
        const int si = br * 64 + (kb ^ ((br & 7) << 3));
        const bf16x8 fh = *(bf16x8*)&Bfh[si];
        const bf16x8 fl = *(bf16x8*)&Bfl[si];
        const bf16x8 gh = *(bf16x8*)&Bgh[si];
        const bf16x8 gl = *(bf16x8*)&Bgl[si];
#pragma unroll
        for (int rb = 0; rb < 2; ++rb) {
          accf[rb][cb] = __builtin_amdgcn_mfma_f32_16x16x32_bf16(al2[rb], fh, accf[rb][cb], 0, 0, 0);
          accf[rb][cb] = __builtin_amdgcn_mfma_f32_16x16x32_bf16(ah[rb], fl, accf[rb][cb], 0, 0, 0);
          accf[rb][cb] = __builtin_amdgcn_mfma_f32_16x16x32_bf16(ah[rb], fh, accf[rb][cb], 0, 0, 0);
          accg[rb][cb] = __builtin_amdgcn_mfma_f32_16x16x32_bf16(al2[rb], gh, accg[rb][cb], 0, 0, 0);
          accg[rb][cb] = __builtin_amdgcn_mfma_f32_16x16x32_bf16(ah[rb], gl, accg[rb][cb], 0, 0, 0);
          accg[rb][cb] = __builtin_amdgcn_mfma_f32_16x16x32_bf16(ah[rb], gh, accg[rb][cb], 0, 0, 0);
        }
      }
    }
  }
#pragma unroll
  for (int cb = 0; cb < 4; ++cb) {
    const int col = n0 + wc * 64 + cb * 16 + l15;
    const float bf4 = bfc[col];
    const float bg4 = bg[col];
#pragma unroll
    for (int rb = 0; rb < 2; ++rb)
#pragma unroll
      for (int ri = 0; ri < 4; ++ri) {
        const int row = r0 + wr * 32 + rb * 16 + l4 * 4 + ri;
        const float f = accf[rb][cb][ri] + bf4;
        const float g = accg[rb][cb][ri] + bg4;
        out[(size_t)row * 512 + col] = tanhf(f) / (1.f + __expf(-g));
      }
  }
}

extern "C" void kernel_launch(void* const* d_in, const int* in_sizes, int n_in,
                              void* d_out, int out_size, void* d_ws, size_t ws_size,
                              hipStream_t stream) {
  const float* q   = (const float*)d_in[0];
  const float* k   = (const float*)d_in[1];
  const float* v   = (const float*)d_in[2];
  const float* Wq  = (const float*)d_in[3];
  const float* bq  = (const float*)d_in[4];
  const float* Wk  = (const float*)d_in[5];
  const float* bk  = (const float*)d_in[6];
  const float* Wv  = (const float*)d_in[7];
  const float* bv  = (const float*)d_in[8];
  const float* Wfc = (const float*)d_in[9];
  const float* bfc = (const float*)d_in[10];
  const float* Wg  = (const float*)d_in[11];
  const float* bg  = (const float*)d_in[12];

  float* out  = (float*)d_out;
  float* attn = out + OUT0;                     // (32,1024,1024) final output 1
  unsigned short* S16 = (unsigned short*)attn;  // input splits, dead before scores

  unsigned short* U = (unsigned short*)d_ws;
  unsigned short* qhh = U;                      // 2M ushorts each (4MB)
  unsigned short* qhl = U + (1u << 21);
  unsigned short* khh = U + (2u << 21);
  unsigned short* khl = U + (3u << 21);
  float* vh = (float*)d_ws + (1u << 22);        // 8MB f32, after the 16MB of splits
  unsigned short* ofhi = U;                     // overlay qhh (qh dead after scores)
  unsigned short* oflo = U + (1u << 21);        // overlay qhl
  unsigned short* W2   = U + (2u << 21);        // overlay khh/khl (kh dead after scores)

  convert6_kernel<<<dim3(2048, 1, 6), 256, 0, stream>>>(q, k, v, Wq, Wk, Wv, S16);
  qkv_mfma_kernel<<<dim3(64, 4, 3), 256, 0, stream>>>(S16, bq, bk, bv, qhh, qhl, khh, khl, vh);
  scores_mfma_kernel<<<dim3(16, 16, 32), 256, 0, stream>>>(qhh, qhl, khh, khl, attn);
  convertW2_kernel<<<dim3(256, 1, 2), 256, 0, stream>>>(Wfc, Wg, W2);
  sparse_row_kernel<<<dim3(8192), 256, 0, stream>>>(attn, vh, ofhi, oflo);
  out_proj_mfma_kernel<<<dim3(64, 4), 256, 0, stream>>>(ofhi, W2, bfc, bg, out);
}